// Round 7
// baseline (7842.990 us; speedup 1.0000x reference)
//
#include <hip/hip_runtime.h>
#include <math.h>

#define NB   4096
#define NIN  768
#define NLAT 24576
#define K2   1536   // [Ah|Al] x [Bh|Bh]
#define KT2  24     // K2/64

// f32 fallback GEMM tiling
#define BM 128
#define BN 128
#define BK 16
#define LDT 132

#define CAND_CAP 160
#define BAND_CAP 160
#define MAIN_CAP 64
#define AUX_CAP  1024
#define SELT     1024
#define EPT      24     // elements per thread = NLAT/SELT
#define GRP      6      // float4 groups per thread

typedef __bf16 bf16x8 __attribute__((ext_vector_type(8)));
typedef float  f32x4  __attribute__((ext_vector_type(4)));

__device__ __forceinline__ unsigned fkey(float f) {
  unsigned u = __float_as_uint(f);
  return u ^ ((unsigned)((int)u >> 31) | 0x80000000u);  // monotone total order
}
__device__ __forceinline__ float keyinv(unsigned u) {
  unsigned s = (u & 0x80000000u) ? (u ^ 0x80000000u) : ~u;
  return __uint_as_float(s);
}

#define GLOAD16(g, l) __builtin_amdgcn_global_load_lds( \
    (const __attribute__((address_space(1))) unsigned int*)(g), \
    (__attribute__((address_space(3))) unsigned int*)(l), 16, 0, 0)

// ---------------- dead bitset: bit j = (miss[j] >= 1) ----------------
__global__ __launch_bounds__(256) void k_deadbits(const int* __restrict__ miss,
                                                  unsigned* __restrict__ bits) {
  int j = blockIdx.x * 256 + threadIdx.x;
  unsigned long long b = __ballot(miss[j] >= 1);
  if ((threadIdx.x & 63) == 0) {
    int w = j >> 5;
    bits[w] = (unsigned)b;
    bits[w + 1] = (unsigned)(b >> 32);
  }
}

// ---------------- W_dec [NIN][NLAT] -> Wt [NLAT][NIN] (bf16) ----------------
__global__ __launch_bounds__(256) void k_transpose(const float* __restrict__ src,
                                                   __bf16* __restrict__ dst) {
  __shared__ float tile[32][33];
  int bx = blockIdx.x * 32;  // NLAT
  int by = blockIdx.y * 32;  // NIN
  int tx = threadIdx.x, ty = threadIdx.y;
  for (int i = ty; i < 32; i += 8)
    tile[i][tx] = src[(size_t)(by + i) * NLAT + bx + tx];
  __syncthreads();
  for (int i = ty; i < 32; i += 8)
    dst[(size_t)(bx + i) * NIN + by + tx] = (__bf16)tile[tx][i];
}

// ---- pack (x-b) into A2 tiles [mt][kt][128][64], pre-swizzled LDS image ----
__global__ __launch_bounds__(256) void k_pack_a(const float* __restrict__ x,
    const float* __restrict__ bvec, __bf16* __restrict__ A2) {
  const int mt = blockIdx.x, kt = blockIdx.y, t = threadIdx.x;
  __bf16* out = A2 + (((size_t)mt * KT2 + kt) << 13);
#pragma unroll
  for (int i = 0; i < 32; ++i) {
    int idx = i * 256 + t;
    int r = idx >> 6, c2 = idx & 63;
    int kk = c2 ^ ((r & 7) << 3);
    int kg = kt * 64 + kk;
    int k = kg >= 768 ? kg - 768 : kg;
    bool lo = (kg >= 768);                            // A = [Ah | Al]
    float v = x[(size_t)(mt * 128 + r) * NIN + k] - bvec[k];
    __bf16 h = (__bf16)v;
    out[idx] = lo ? (__bf16)(v - (float)h) : h;
  }
}

__global__ __launch_bounds__(256) void k_pack_b(const float* __restrict__ We,
    __bf16* __restrict__ B2) {
  const int nt = blockIdx.x, kt = blockIdx.y, t = threadIdx.x;
  __bf16* out = B2 + (((size_t)nt * KT2 + kt) << 13);
#pragma unroll
  for (int i = 0; i < 32; ++i) {
    int idx = i * 256 + t;
    int r = idx >> 6, c2 = idx & 63;
    int kk = c2 ^ ((r & 7) << 3);
    int kg = kt * 64 + kk;
    int k = kg >= 768 ? kg - 768 : kg;                // B = [Bh | Bh]
    float v = We[(size_t)(nt * 128 + r) * NIN + k];
    out[idx] = (__bf16)v;
  }
}

// ---------------- bf16 MFMA GEMM: apre = A2 @ B2^T + be ----------------
__global__ __launch_bounds__(256) void k_gemm_bf16(
    const __bf16* __restrict__ A2, const __bf16* __restrict__ B2,
    const float* __restrict__ be, float* __restrict__ apre) {
  __shared__ char sA[16384];
  __shared__ char sB[16384];
  const int t = threadIdx.x;
  const int lane = t & 63, wave = t >> 6;
  const int mt = blockIdx.x, nt = blockIdx.y;
  const int wm = wave >> 1, wn = wave & 1;

  int aoff[4][2], boff[4][2];
#pragma unroll
  for (int f = 0; f < 4; ++f) {
    int ra = wm * 64 + f * 16 + (lane & 15);
    int rb = wn * 64 + f * 16 + (lane & 15);
#pragma unroll
    for (int kk = 0; kk < 2; ++kk) {
      int c = kk * 64 + (lane >> 4) * 16;
      aoff[f][kk] = ra * 128 + (c ^ ((ra & 7) << 4));
      boff[f][kk] = rb * 128 + (c ^ ((rb & 7) << 4));
    }
  }
  f32x4 acc[4][4] = {};
  const char* gA = (const char*)(A2 + (((size_t)mt * KT2) << 13));
  const char* gB = (const char*)(B2 + (((size_t)nt * KT2) << 13));
  for (int kt = 0; kt < KT2; ++kt) {
    const char* tA = gA + ((size_t)kt << 14);
    const char* tB = gB + ((size_t)kt << 14);
#pragma unroll
    for (int i = 0; i < 4; ++i) {
      int chunk = (i * 4 + wave) * 1024;
      GLOAD16(tA + chunk + lane * 16, sA + chunk);
      GLOAD16(tB + chunk + lane * 16, sB + chunk);
    }
    __syncthreads();
#pragma unroll
    for (int kk = 0; kk < 2; ++kk) {
      bf16x8 a[4], b[4];
#pragma unroll
      for (int f = 0; f < 4; ++f) {
        a[f] = *(const bf16x8*)(sA + aoff[f][kk]);
        b[f] = *(const bf16x8*)(sB + boff[f][kk]);
      }
#pragma unroll
      for (int mi = 0; mi < 4; ++mi)
#pragma unroll
        for (int ni = 0; ni < 4; ++ni)
          acc[mi][ni] = __builtin_amdgcn_mfma_f32_16x16x32_bf16(a[mi], b[ni], acc[mi][ni], 0, 0, 0);
    }
    __syncthreads();
  }
  const int m0 = mt * 128 + wm * 64, n0 = nt * 128 + wn * 64;
#pragma unroll
  for (int ni = 0; ni < 4; ++ni) {
    int n = n0 + ni * 16 + (lane & 15);
    float bb = be[n];
#pragma unroll
    for (int mi = 0; mi < 4; ++mi) {
      int mbase = m0 + mi * 16 + (lane >> 4) * 4;
#pragma unroll
      for (int q = 0; q < 4; ++q)
        apre[(size_t)(mbase + q) * NLAT + n] = acc[mi][ni][q] + bb;
    }
  }
}

// ---------------- f32 fallback GEMM ----------------
__global__ __launch_bounds__(256) void k_encgemm_f32(
    const float* __restrict__ x, const float* __restrict__ bvec,
    const float* __restrict__ We, const float* __restrict__ be,
    float* __restrict__ apre) {
  __shared__ float As[BK][LDT];
  __shared__ float Bs[BK][LDT];
  const int t = threadIdx.x;
  const int m0 = blockIdx.x * BM;
  const int n0 = blockIdx.y * BN;
  const int lane = t & 63, wave = t >> 6;
  const int cn = ((wave & 1) * 8 + (lane & 7)) * 8;
  const int cm = ((wave >> 1) * 8 + (lane >> 3)) * 8;
  float acc[8][8] = {};
  const float* xb = x + (size_t)m0 * NIN;
  const float* wb = We + (size_t)n0 * NIN;
  for (int k0 = 0; k0 < NIN; k0 += BK) {
#pragma unroll
    for (int i = 0; i < 2; ++i) {
      int e = t + i * 256;
      int row = e >> 2, q = e & 3;
      float4 bv = *(const float4*)(bvec + k0 + q * 4);
      float4 av = *(const float4*)(xb + (size_t)row * NIN + k0 + q * 4);
      av.x -= bv.x; av.y -= bv.y; av.z -= bv.z; av.w -= bv.w;
      As[q * 4 + 0][row] = av.x; As[q * 4 + 1][row] = av.y;
      As[q * 4 + 2][row] = av.z; As[q * 4 + 3][row] = av.w;
      float4 wv = *(const float4*)(wb + (size_t)row * NIN + k0 + q * 4);
      Bs[q * 4 + 0][row] = wv.x; Bs[q * 4 + 1][row] = wv.y;
      Bs[q * 4 + 2][row] = wv.z; Bs[q * 4 + 3][row] = wv.w;
    }
    __syncthreads();
#pragma unroll
    for (int kk = 0; kk < BK; ++kk) {
      float a0[8], b0[8];
      *(float4*)&a0[0] = *(const float4*)&As[kk][cm];
      *(float4*)&a0[4] = *(const float4*)&As[kk][cm + 4];
      *(float4*)&b0[0] = *(const float4*)&Bs[kk][cn];
      *(float4*)&b0[4] = *(const float4*)&Bs[kk][cn + 4];
#pragma unroll
      for (int i = 0; i < 8; ++i)
#pragma unroll
        for (int j = 0; j < 8; ++j)
          acc[i][j] = fmaf(a0[i], b0[j], acc[i][j]);
    }
    __syncthreads();
  }
  float bb[8];
  *(float4*)&bb[0] = *(const float4*)(be + n0 + cn);
  *(float4*)&bb[4] = *(const float4*)(be + n0 + cn + 4);
#pragma unroll
  for (int i = 0; i < 8; ++i) {
    float4 v0 = make_float4(acc[i][0] + bb[0], acc[i][1] + bb[1],
                            acc[i][2] + bb[2], acc[i][3] + bb[3]);
    float4 v1 = make_float4(acc[i][4] + bb[4], acc[i][5] + bb[5],
                            acc[i][6] + bb[6], acc[i][7] + bb[7]);
    float* orow = apre + (size_t)(m0 + cm + i) * NLAT + n0 + cn;
    *(float4*)orow = v0;
    *(float4*)(orow + 4) = v1;
  }
}

// ------------- per-row: 1024-thread register-resident top-k select ----
// __launch_bounds__(1024, 4): 4 waves/EU -> 16 waves/CU (1 block/CU) and a
// 128-VGPR budget so key[EPT] stays register-resident (R6's 64-VGPR budget
// spilled it -> 20 GB of scratch traffic).
// apre and mask alias — no __restrict__ on either; each block owns its row.
__global__ __launch_bounds__(SELT, 4) void k_select6(
    const float* apre, const float* __restrict__ x,
    const float* __restrict__ bvec, const float* __restrict__ We,
    const float* __restrict__ be, const unsigned* __restrict__ dbits,
    const int* __restrict__ kptr, const int* __restrict__ akptr,
    float* __restrict__ alpha, float* mask,
    int* __restrict__ cnts, int* __restrict__ mIdxG, float* __restrict__ mValG,
    int* __restrict__ aIdxG, float* __restrict__ aValG) {
  const int t = threadIdx.x;
  const int r = blockIdx.x;
  const int lane = t & 63, wave = t >> 6;   // 16 waves

  __shared__ int wred[2][48];
  __shared__ unsigned wredu[2][16];
  __shared__ int ctrl[8];
  __shared__ unsigned candK[CAND_CAP];
  __shared__ int candI[CAND_CAP];
  __shared__ int bandI[BAND_CAP];
  __shared__ double bandV[BAND_CAP];
  __shared__ unsigned char bandSel[BAND_CAP];

  // ---- load row as sort keys (24 regs) + dead bits (1 reg) ----
  unsigned key[EPT];
  const float4* rowp = (const float4*)(apre + (size_t)r * NLAT);
  unsigned dm = 0;
#pragma unroll
  for (int i = 0; i < GRP; ++i) {
    int g = t + SELT * i;
    float4 v = rowp[g];
    key[4 * i + 0] = fkey(v.x); key[4 * i + 1] = fkey(v.y);
    key[4 * i + 2] = fkey(v.z); key[4 * i + 3] = fkey(v.w);
    unsigned nb = (dbits[g >> 3] >> ((g & 7) * 4)) & 0xFu;
    dm |= nb << (4 * i);
  }
  int kmain = kptr[0]; if (kmain > MAIN_CAP) kmain = MAIN_CAP;
  int kaux  = akptr[0]; if (kaux > AUX_CAP)  kaux  = AUX_CAP;

  int par = 0, paru = 0;

  for (int pass = 0; pass < 2; ++pass) {
    int kreq, nelig;
    if (pass == 0) { kreq = kmain; nelig = NLAT; }
    else {
      // marker 0u (< any finite key) for non-dead latents
#pragma unroll
      for (int e = 0; e < EPT; ++e)
        if (!((dm >> e) & 1u)) key[e] = 0u;
      int pc = __popc(dm & 0xFFFFFFu);
#pragma unroll
      for (int o = 32; o; o >>= 1) pc += __shfl_xor(pc, o);
      if (lane == 0) wred[par][wave] = pc;
      __syncthreads();
      nelig = 0;
#pragma unroll
      for (int w = 0; w < 16; ++w) nelig += wred[par][w];
      par ^= 1;
      kreq = kaux;
    }
    if (kreq > nelig) kreq = nelig;
    if (kreq <= 0) {
      if (t == 0) cnts[2 * r + pass] = 0;
      continue;
    }

    // ---- block max/min of eligible keys ----
    unsigned mx = 0u, mn = 0xFFFFFFFFu;
#pragma unroll
    for (int e = 0; e < EPT; ++e) {
      unsigned kk = key[e];
      bool el = (pass == 0) || ((dm >> e) & 1u);
      if (el) { mx = kk > mx ? kk : mx; mn = kk < mn ? kk : mn; }
    }
#pragma unroll
    for (int o = 32; o; o >>= 1) {
      unsigned om = __shfl_xor(mx, o); mx = om > mx ? om : mx;
      unsigned on = __shfl_xor(mn, o); mn = on < mn ? on : mn;
    }
    if (lane == 0) { wredu[paru][wave] = mx; wredu[paru ^ 1][wave] = mn; }
    __syncthreads();
    mx = 0u; mn = 0xFFFFFFFFu;
#pragma unroll
    for (int w = 0; w < 16; ++w) {
      unsigned a = wredu[paru][w], b = wredu[paru ^ 1][w];
      mx = a > mx ? a : mx; mn = b < mn ? b : mn;
    }
    __syncthreads();

    // ---- value-space 3-threshold probe for the k-th boundary window ----
    unsigned Tlo = mn, Thi = mx + 1u;
    int cLo = nelig, cHi = 0;
    float vlo = keyinv(mn), vhi = keyinv(mx);
    for (int it = 0; it < 24 && (cLo - cHi) > (CAND_CAP - 8); ++it) {
      float v1 = 0.75f * vlo + 0.25f * vhi;
      float v2 = 0.50f * vlo + 0.50f * vhi;
      float v3 = 0.25f * vlo + 0.75f * vhi;
      unsigned T1 = fkey(v1), T2 = fkey(v2), T3 = fkey(v3);
      if (!(T1 > Tlo && T3 < Thi && T1 <= T2 && T2 <= T3)) break;
      int c1 = 0, c2 = 0, c3 = 0;
#pragma unroll
      for (int e = 0; e < EPT; ++e) {
        unsigned kk = key[e];
        c1 += (kk >= T1) ? 1 : 0;
        c2 += (kk >= T2) ? 1 : 0;
        c3 += (kk >= T3) ? 1 : 0;
      }
#pragma unroll
      for (int o = 32; o; o >>= 1) {
        c1 += __shfl_xor(c1, o); c2 += __shfl_xor(c2, o); c3 += __shfl_xor(c3, o);
      }
      if (lane == 0) {
        wred[par][wave * 3 + 0] = c1;
        wred[par][wave * 3 + 1] = c2;
        wred[par][wave * 3 + 2] = c3;
      }
      __syncthreads();
      c1 = 0; c2 = 0; c3 = 0;
#pragma unroll
      for (int w = 0; w < 16; ++w) {
        c1 += wred[par][w * 3 + 0];
        c2 += wred[par][w * 3 + 1];
        c3 += wred[par][w * 3 + 2];
      }
      par ^= 1;
      // counts descending: c1 >= c2 >= c3
      if (c3 >= kreq)      { Tlo = T3; cLo = c3; vlo = v3; }
      else if (c2 >= kreq) { Tlo = T2; cLo = c2; vlo = v2; Thi = T3; cHi = c3; vhi = v3; }
      else if (c1 >= kreq) { Tlo = T1; cLo = c1; vlo = v1; Thi = T2; cHi = c2; vhi = v2; }
      else                 { Thi = T1; cHi = c1; vhi = v1; }
    }

    // ---- extract window candidates, exact-rank the k-th key ----
    if (t == 0) ctrl[0] = 0;
    __syncthreads();
#pragma unroll
    for (int i = 0; i < GRP; ++i)
#pragma unroll
      for (int q = 0; q < 4; ++q) {
        unsigned kk = key[4 * i + q];
        if (kk >= Tlo && kk < Thi) {
          int p = atomicAdd(&ctrl[0], 1);
          if (p < CAND_CAP) { candK[p] = kk; candI[p] = 4 * (t + SELT * i) + q; }
        }
      }
    __syncthreads();
    int cc = ctrl[0]; if (cc > CAND_CAP) cc = CAND_CAP;
    int need = kreq - cHi;
    if (need < 1) need = 1;
    if (need > cc) need = cc;
    if (t < cc) {
      unsigned ki = candK[t]; int ii = candI[t];
      int rank = 0;
      for (int qq = 0; qq < cc; ++qq) {
        unsigned kq = candK[qq];
        rank += (kq > ki || (kq == ki && candI[qq] < ii)) ? 1 : 0;
      }
      if (rank == need - 1) ctrl[1] = (int)ki;
    }
    __syncthreads();

    // ---- f64 band refinement around V* ----
    float Vs = keyinv((unsigned)ctrl[1]);
    float eps = 1e-2f + 2e-3f * fabsf(Vs);
    unsigned KhiB = fkey(Vs + eps), KloB = fkey(Vs - eps);
    if (t == 0) { ctrl[2] = 0; ctrl[3] = 0; }
    __syncthreads();
    int abv = 0;
#pragma unroll
    for (int i = 0; i < GRP; ++i)
#pragma unroll
      for (int q = 0; q < 4; ++q) {
        unsigned kk = key[4 * i + q];
        if (kk > KhiB) ++abv;
        else if (kk >= KloB) {
          int p = atomicAdd(&ctrl[3], 1);
          if (p < BAND_CAP) bandI[p] = 4 * (t + SELT * i) + q;
        }
      }
#pragma unroll
    for (int o = 32; o; o >>= 1) abv += __shfl_xor(abv, o);
    if (lane == 0) atomicAdd(&ctrl[2], abv);
    __syncthreads();
    int nAb = ctrl[2];
    int bc = ctrl[3]; if (bc > BAND_CAP) bc = BAND_CAP;
    int needB = kreq - nAb;
    if (needB < 0) needB = 0;
    if (needB > bc) needB = bc;

    // wave-per-member f64 dot: lane l covers cols l, l+64, ... (coalesced)
    {
      const float* xr = x + (size_t)r * NIN;
      for (int m = wave; m < bc; m += 16) {
        int j = bandI[m];
        const float* wr = We + (size_t)j * NIN;
        double s = 0.0;
#pragma unroll
        for (int jj = 0; jj < NIN / 64; ++jj) {
          int col = lane + 64 * jj;
          s += ((double)xr[col] - (double)bvec[col]) * (double)wr[col];
        }
#pragma unroll
        for (int o = 32; o; o >>= 1) s += __shfl_xor(s, o);
        if (lane == 0) bandV[m] = s + (double)be[j];
      }
    }
    __syncthreads();
    if (t < bc) {
      double vi = bandV[t]; int ii = bandI[t];
      double tie = fabs(vi) * 4e-8 + 1e-12;
      int rank = 0;
      for (int qq = 0; qq < bc; ++qq) {
        double d = bandV[qq] - vi;
        rank += ((fabs(d) <= tie) ? (bandI[qq] < ii) : (d > 0.0)) ? 1 : 0;
      }
      bandSel[t] = (rank < needB) ? 1 : 0;
    }
    if (t == 0) ctrl[4] = 0;
    __syncthreads();

    // ---- emit ----
    if (pass == 0) {
      float4* arow = (float4*)(alpha + (size_t)r * NLAT);
      float4* mrow = (float4*)(mask + (size_t)r * NLAT);
#pragma unroll
      for (int i = 0; i < GRP; ++i) {
        float av[4], mv[4];
#pragma unroll
        for (int q = 0; q < 4; ++q) {
          unsigned kk = key[4 * i + q];
          int j = 4 * (t + SELT * i) + q;
          bool sel = kk > KhiB;
          if (!sel && kk >= KloB) {
            for (int m2 = 0; m2 < bc; ++m2)
              if (bandI[m2] == j) { sel = bandSel[m2] != 0; break; }
          }
          float v = keyinv(kk);
          bool nz = sel && (v != 0.0f);
          av[q] = sel ? v : 0.0f;
          mv[q] = nz ? 1.0f : 0.0f;
          if (nz) {
            int p = atomicAdd(&ctrl[4], 1);
            if (p < MAIN_CAP) { mIdxG[r * MAIN_CAP + p] = j; mValG[r * MAIN_CAP + p] = v; }
          }
        }
        arow[t + SELT * i] = make_float4(av[0], av[1], av[2], av[3]);
        mrow[t + SELT * i] = make_float4(mv[0], mv[1], mv[2], mv[3]);
      }
    } else {
#pragma unroll
      for (int i = 0; i < GRP; ++i)
#pragma unroll
        for (int q = 0; q < 4; ++q) {
          unsigned kk = key[4 * i + q];
          if (kk == 0u) continue;  // marker (non-dead)
          int j = 4 * (t + SELT * i) + q;
          bool sel = kk > KhiB;
          if (!sel && kk >= KloB) {
            for (int m2 = 0; m2 < bc; ++m2)
              if (bandI[m2] == j) { sel = bandSel[m2] != 0; break; }
          }
          float v = keyinv(kk);
          if (sel && v != 0.0f) {
            int p = atomicAdd(&ctrl[4], 1);
            if (p < AUX_CAP) { aIdxG[r * AUX_CAP + p] = j; aValG[r * AUX_CAP + p] = v; }
          }
        }
    }
    __syncthreads();
    if (t == 0) {
      int c = ctrl[4];
      int cap = (pass == 0) ? MAIN_CAP : AUX_CAP;
      cnts[2 * r + pass] = c < cap ? c : cap;
    }
    __syncthreads();
  }
}

// ------------- decode: xhat/auxo from (idx,val) lists; no VGPR cap ----
__global__ __launch_bounds__(256) void k_decode(
    const int* __restrict__ cnts, const int* __restrict__ mIdxG,
    const float* __restrict__ mValG, const int* __restrict__ aIdxG,
    const float* __restrict__ aValG, const float* __restrict__ bvec,
    const __bf16* __restrict__ Wt, const float* __restrict__ Wd,
    float* __restrict__ xhat, float* __restrict__ auxo) {
  const int r = blockIdx.x, t = threadIdx.x;
  __shared__ int sMi[MAIN_CAP];
  __shared__ float sMv[MAIN_CAP];
  __shared__ int sAi[AUX_CAP];
  __shared__ float sAv[AUX_CAP];
  int kc = cnts[2 * r], ac = cnts[2 * r + 1];
  if (t < MAIN_CAP && t < kc) { sMi[t] = mIdxG[r * MAIN_CAP + t]; sMv[t] = mValG[r * MAIN_CAP + t]; }
  for (int i = t; i < ac; i += 256) { sAi[i] = aIdxG[r * AUX_CAP + i]; sAv[i] = aValG[r * AUX_CAP + i]; }
  __syncthreads();

  float o0 = 0.f, o1 = 0.f, o2 = 0.f;   // cols t, t+256, t+512
  float a0 = 0.f, a1 = 0.f, a2 = 0.f;
  if (Wt) {
    int i = 0;
    for (; i + 4 <= kc; i += 4) {
      int i0 = sMi[i], i1 = sMi[i + 1], i2 = sMi[i + 2], i3 = sMi[i + 3];
      float v0 = sMv[i], v1 = sMv[i + 1], v2 = sMv[i + 2], v3 = sMv[i + 3];
      const __bf16* p0 = Wt + (size_t)i0 * NIN;
      const __bf16* p1 = Wt + (size_t)i1 * NIN;
      const __bf16* p2 = Wt + (size_t)i2 * NIN;
      const __bf16* p3 = Wt + (size_t)i3 * NIN;
      float w00 = p0[t], w01 = p0[t + 256], w02 = p0[t + 512];
      float w10 = p1[t], w11 = p1[t + 256], w12 = p1[t + 512];
      float w20 = p2[t], w21 = p2[t + 256], w22 = p2[t + 512];
      float w30 = p3[t], w31 = p3[t + 256], w32 = p3[t + 512];
      o0 = fmaf(v0, w00, o0); o1 = fmaf(v0, w01, o1); o2 = fmaf(v0, w02, o2);
      o0 = fmaf(v1, w10, o0); o1 = fmaf(v1, w11, o1); o2 = fmaf(v1, w12, o2);
      o0 = fmaf(v2, w20, o0); o1 = fmaf(v2, w21, o1); o2 = fmaf(v2, w22, o2);
      o0 = fmaf(v3, w30, o0); o1 = fmaf(v3, w31, o1); o2 = fmaf(v3, w32, o2);
    }
    for (; i < kc; ++i) {
      const __bf16* p = Wt + (size_t)sMi[i] * NIN;
      float v = sMv[i];
      o0 = fmaf(v, (float)p[t], o0);
      o1 = fmaf(v, (float)p[t + 256], o1);
      o2 = fmaf(v, (float)p[t + 512], o2);
    }
    i = 0;
    for (; i + 4 <= ac; i += 4) {
      int i0 = sAi[i], i1 = sAi[i + 1], i2 = sAi[i + 2], i3 = sAi[i + 3];
      float v0 = sAv[i], v1 = sAv[i + 1], v2 = sAv[i + 2], v3 = sAv[i + 3];
      const __bf16* p0 = Wt + (size_t)i0 * NIN;
      const __bf16* p1 = Wt + (size_t)i1 * NIN;
      const __bf16* p2 = Wt + (size_t)i2 * NIN;
      const __bf16* p3 = Wt + (size_t)i3 * NIN;
      float w00 = p0[t], w01 = p0[t + 256], w02 = p0[t + 512];
      float w10 = p1[t], w11 = p1[t + 256], w12 = p1[t + 512];
      float w20 = p2[t], w21 = p2[t + 256], w22 = p2[t + 512];
      float w30 = p3[t], w31 = p3[t + 256], w32 = p3[t + 512];
      a0 = fmaf(v0, w00, a0); a1 = fmaf(v0, w01, a1); a2 = fmaf(v0, w02, a2);
      a0 = fmaf(v1, w10, a0); a1 = fmaf(v1, w11, a1); a2 = fmaf(v1, w12, a2);
      a0 = fmaf(v2, w20, a0); a1 = fmaf(v2, w21, a1); a2 = fmaf(v2, w22, a2);
      a0 = fmaf(v3, w30, a0); a1 = fmaf(v3, w31, a1); a2 = fmaf(v3, w32, a2);
    }
    for (; i < ac; ++i) {
      const __bf16* p = Wt + (size_t)sAi[i] * NIN;
      float v = sAv[i];
      a0 = fmaf(v, (float)p[t], a0);
      a1 = fmaf(v, (float)p[t + 256], a1);
      a2 = fmaf(v, (float)p[t + 512], a2);
    }
  } else {  // fallback: strided gather from W_dec [NIN][NLAT]
    for (int i = 0; i < kc; ++i) {
      float v = sMv[i]; int ix = sMi[i];
      o0 = fmaf(v, Wd[(size_t)t * NLAT + ix], o0);
      o1 = fmaf(v, Wd[(size_t)(t + 256) * NLAT + ix], o1);
      o2 = fmaf(v, Wd[(size_t)(t + 512) * NLAT + ix], o2);
    }
    for (int i = 0; i < ac; ++i) {
      float v = sAv[i]; int ix = sAi[i];
      a0 = fmaf(v, Wd[(size_t)t * NLAT + ix], a0);
      a1 = fmaf(v, Wd[(size_t)(t + 256) * NLAT + ix], a1);
      a2 = fmaf(v, Wd[(size_t)(t + 512) * NLAT + ix], a2);
    }
  }
  float b0 = bvec[t], b1 = bvec[t + 256], b2 = bvec[t + 512];
  xhat[(size_t)r * NIN + t] = o0 + b0;
  xhat[(size_t)r * NIN + t + 256] = o1 + b1;
  xhat[(size_t)r * NIN + t + 512] = o2 + b2;
  auxo[(size_t)r * NIN + t] = a0 + b0;
  auxo[(size_t)r * NIN + t + 256] = a1 + b1;
  auxo[(size_t)r * NIN + t + 512] = a2 + b2;
}

extern "C" void kernel_launch(void* const* d_in, const int* in_sizes, int n_in,
                              void* d_out, int out_size, void* d_ws, size_t ws_size,
                              hipStream_t stream) {
  const float* x  = (const float*)d_in[0];
  const float* bv = (const float*)d_in[1];
  const float* We = (const float*)d_in[2];
  const float* be = (const float*)d_in[3];
  const float* Wd = (const float*)d_in[4];
  const int* miss = (const int*)d_in[5];
  const int* kp   = (const int*)d_in[6];
  const int* akp  = (const int*)d_in[7];

  float* out   = (float*)d_out;
  float* xhat  = out;                          // [4096 x 768]
  float* alpha = out + (size_t)3145728;        // [4096 x 24576]
  float* apre  = out + (size_t)103809024;      // fired_mask region; alpha_pre scratch
  float* auxo  = out + (size_t)204472320;      // [4096 x 768]

  // ws layout: dbits 64K | cnts 64K | mIdx 1M | mVal 1M | aIdx 16M | aVal 16M
  //            | Wt bf16 36M | A2 12M | B2 72M   (~154 MB total)
  char* wsb = (char*)d_ws;
  unsigned* dbits = (unsigned*)wsb;
  int*   cnts  = (int*)(wsb + 65536);
  int*   mIdxG = (int*)(wsb + 131072);
  float* mValG = (float*)(wsb + 131072 + (size_t)NB * MAIN_CAP * 4);
  int*   aIdxG = (int*)(wsb + 131072 + (size_t)NB * MAIN_CAP * 8);
  float* aValG = (float*)(wsb + 131072 + (size_t)NB * MAIN_CAP * 8 + (size_t)NB * AUX_CAP * 4);
  size_t offWt = 131072 + (size_t)NB * MAIN_CAP * 8 + (size_t)NB * AUX_CAP * 8;
  size_t offA2 = offWt + (size_t)NLAT * NIN * 2;
  size_t offB2 = offA2 + (size_t)NB * K2 * 2;
  size_t needFull = offB2 + (size_t)NLAT * K2 * 2;
  bool haveWt   = ws_size >= offA2;
  bool haveFull = ws_size >= needFull;
  __bf16* Wt = haveWt ? (__bf16*)(wsb + offWt) : nullptr;
  __bf16* A2 = (__bf16*)(wsb + offA2);
  __bf16* B2 = (__bf16*)(wsb + offB2);

  k_deadbits<<<96, 256, 0, stream>>>(miss, dbits);
  if (haveFull) {
    k_pack_a<<<dim3(32, KT2), 256, 0, stream>>>(x, bv, A2);
    k_pack_b<<<dim3(192, KT2), 256, 0, stream>>>(We, B2);
  }
  if (haveWt)
    k_transpose<<<dim3(NLAT / 32, NIN / 32), dim3(32, 8), 0, stream>>>(Wd, Wt);

  if (haveFull)
    k_gemm_bf16<<<dim3(32, 192), 256, 0, stream>>>(A2, B2, be, apre);
  else
    k_encgemm_f32<<<dim3(NB / BM, NLAT / BN), 256, 0, stream>>>(x, bv, We, be, apre);

  k_select6<<<NB, SELT, 0, stream>>>(apre, x, bv, We, be, dbits, kp, akp,
                                     alpha, apre, cnts, mIdxG, mValG, aIdxG, aValG);
  k_decode<<<NB, 256, 0, stream>>>(cnts, mIdxG, mValG, aIdxG, aValG, bv,
                                   Wt, Wd, xhat, auxo);
}

// Round 8
// 2766.351 us; speedup vs baseline: 2.8351x; 2.8351x over previous
//
#include <hip/hip_runtime.h>
#include <math.h>

#define NB   4096
#define NIN  768
#define NLAT 24576
#define K2   1536   // [Ah|Al] x [Bh|Bh]
#define KT2  24     // K2/64

// f32 fallback GEMM tiling
#define BM 128
#define BN 128
#define BK 16
#define LDT 132

#define CAND_CAP 160
#define BAND_CAP 160
#define MAIN_CAP 64
#define AUX_CAP  1024
#define SELT     1024
#define GRP      6      // uint4 groups per thread (24 elems)

// dynamic LDS layout for k_select7
#define OFF_KEYS   0
#define OFF_WRED   98304            // int [2][48]
#define OFF_WREDU  (98304+384)      // unsigned [2][16]
#define OFF_CTRL   (98304+512)      // int [8]
#define OFF_CANDK  (98304+544)      // unsigned [CAND_CAP]
#define OFF_CANDI  (98304+544+640)  // int [CAND_CAP]
#define OFF_BANDI  (98304+544+1280) // int [BAND_CAP]
#define OFF_BANDV  (98304+544+1920) // double [BAND_CAP]  (8B aligned: 100768)
#define OFF_BANDS  (98304+544+1920+1280) // uchar [BAND_CAP]
#define SMEM_SEL   102400

typedef __bf16 bf16x8 __attribute__((ext_vector_type(8)));
typedef float  f32x4  __attribute__((ext_vector_type(4)));

__device__ __forceinline__ unsigned fkey(float f) {
  unsigned u = __float_as_uint(f);
  return u ^ ((unsigned)((int)u >> 31) | 0x80000000u);  // monotone total order
}
__device__ __forceinline__ float keyinv(unsigned u) {
  unsigned s = (u & 0x80000000u) ? (u ^ 0x80000000u) : ~u;
  return __uint_as_float(s);
}

#define GLOAD16(g, l) __builtin_amdgcn_global_load_lds( \
    (const __attribute__((address_space(1))) unsigned int*)(g), \
    (__attribute__((address_space(3))) unsigned int*)(l), 16, 0, 0)

// ---------------- dead bitset: bit j = (miss[j] >= 1) ----------------
__global__ __launch_bounds__(256) void k_deadbits(const int* __restrict__ miss,
                                                  unsigned* __restrict__ bits) {
  int j = blockIdx.x * 256 + threadIdx.x;
  unsigned long long b = __ballot(miss[j] >= 1);
  if ((threadIdx.x & 63) == 0) {
    int w = j >> 5;
    bits[w] = (unsigned)b;
    bits[w + 1] = (unsigned)(b >> 32);
  }
}

// ---------------- W_dec [NIN][NLAT] -> Wt [NLAT][NIN] (bf16) ----------------
__global__ __launch_bounds__(256) void k_transpose(const float* __restrict__ src,
                                                   __bf16* __restrict__ dst) {
  __shared__ float tile[32][33];
  int bx = blockIdx.x * 32;  // NLAT
  int by = blockIdx.y * 32;  // NIN
  int tx = threadIdx.x, ty = threadIdx.y;
  for (int i = ty; i < 32; i += 8)
    tile[i][tx] = src[(size_t)(by + i) * NLAT + bx + tx];
  __syncthreads();
  for (int i = ty; i < 32; i += 8)
    dst[(size_t)(bx + i) * NIN + by + tx] = (__bf16)tile[tx][i];
}

// ---- pack (x-b) into A2 tiles [mt][kt][128][64], pre-swizzled LDS image ----
__global__ __launch_bounds__(256) void k_pack_a(const float* __restrict__ x,
    const float* __restrict__ bvec, __bf16* __restrict__ A2) {
  const int mt = blockIdx.x, kt = blockIdx.y, t = threadIdx.x;
  __bf16* out = A2 + (((size_t)mt * KT2 + kt) << 13);
#pragma unroll
  for (int i = 0; i < 32; ++i) {
    int idx = i * 256 + t;
    int r = idx >> 6, c2 = idx & 63;
    int kk = c2 ^ ((r & 7) << 3);
    int kg = kt * 64 + kk;
    int k = kg >= 768 ? kg - 768 : kg;
    bool lo = (kg >= 768);                            // A = [Ah | Al]
    float v = x[(size_t)(mt * 128 + r) * NIN + k] - bvec[k];
    __bf16 h = (__bf16)v;
    out[idx] = lo ? (__bf16)(v - (float)h) : h;
  }
}

__global__ __launch_bounds__(256) void k_pack_b(const float* __restrict__ We,
    __bf16* __restrict__ B2) {
  const int nt = blockIdx.x, kt = blockIdx.y, t = threadIdx.x;
  __bf16* out = B2 + (((size_t)nt * KT2 + kt) << 13);
#pragma unroll
  for (int i = 0; i < 32; ++i) {
    int idx = i * 256 + t;
    int r = idx >> 6, c2 = idx & 63;
    int kk = c2 ^ ((r & 7) << 3);
    int kg = kt * 64 + kk;
    int k = kg >= 768 ? kg - 768 : kg;                // B = [Bh | Bh]
    float v = We[(size_t)(nt * 128 + r) * NIN + k];
    out[idx] = (__bf16)v;
  }
}

// ---------------- bf16 MFMA GEMM: apre = A2 @ B2^T + be ----------------
__global__ __launch_bounds__(256) void k_gemm_bf16(
    const __bf16* __restrict__ A2, const __bf16* __restrict__ B2,
    const float* __restrict__ be, float* __restrict__ apre) {
  __shared__ char sA[16384];
  __shared__ char sB[16384];
  const int t = threadIdx.x;
  const int lane = t & 63, wave = t >> 6;
  const int mt = blockIdx.x, nt = blockIdx.y;
  const int wm = wave >> 1, wn = wave & 1;

  int aoff[4][2], boff[4][2];
#pragma unroll
  for (int f = 0; f < 4; ++f) {
    int ra = wm * 64 + f * 16 + (lane & 15);
    int rb = wn * 64 + f * 16 + (lane & 15);
#pragma unroll
    for (int kk = 0; kk < 2; ++kk) {
      int c = kk * 64 + (lane >> 4) * 16;
      aoff[f][kk] = ra * 128 + (c ^ ((ra & 7) << 4));
      boff[f][kk] = rb * 128 + (c ^ ((rb & 7) << 4));
    }
  }
  f32x4 acc[4][4] = {};
  const char* gA = (const char*)(A2 + (((size_t)mt * KT2) << 13));
  const char* gB = (const char*)(B2 + (((size_t)nt * KT2) << 13));
  for (int kt = 0; kt < KT2; ++kt) {
    const char* tA = gA + ((size_t)kt << 14);
    const char* tB = gB + ((size_t)kt << 14);
#pragma unroll
    for (int i = 0; i < 4; ++i) {
      int chunk = (i * 4 + wave) * 1024;
      GLOAD16(tA + chunk + lane * 16, sA + chunk);
      GLOAD16(tB + chunk + lane * 16, sB + chunk);
    }
    __syncthreads();
#pragma unroll
    for (int kk = 0; kk < 2; ++kk) {
      bf16x8 a[4], b[4];
#pragma unroll
      for (int f = 0; f < 4; ++f) {
        a[f] = *(const bf16x8*)(sA + aoff[f][kk]);
        b[f] = *(const bf16x8*)(sB + boff[f][kk]);
      }
#pragma unroll
      for (int mi = 0; mi < 4; ++mi)
#pragma unroll
        for (int ni = 0; ni < 4; ++ni)
          acc[mi][ni] = __builtin_amdgcn_mfma_f32_16x16x32_bf16(a[mi], b[ni], acc[mi][ni], 0, 0, 0);
    }
    __syncthreads();
  }
  const int m0 = mt * 128 + wm * 64, n0 = nt * 128 + wn * 64;
#pragma unroll
  for (int ni = 0; ni < 4; ++ni) {
    int n = n0 + ni * 16 + (lane & 15);
    float bb = be[n];
#pragma unroll
    for (int mi = 0; mi < 4; ++mi) {
      int mbase = m0 + mi * 16 + (lane >> 4) * 4;
#pragma unroll
      for (int q = 0; q < 4; ++q)
        apre[(size_t)(mbase + q) * NLAT + n] = acc[mi][ni][q] + bb;
    }
  }
}

// ---------------- f32 fallback GEMM ----------------
__global__ __launch_bounds__(256) void k_encgemm_f32(
    const float* __restrict__ x, const float* __restrict__ bvec,
    const float* __restrict__ We, const float* __restrict__ be,
    float* __restrict__ apre) {
  __shared__ float As[BK][LDT];
  __shared__ float Bs[BK][LDT];
  const int t = threadIdx.x;
  const int m0 = blockIdx.x * BM;
  const int n0 = blockIdx.y * BN;
  const int lane = t & 63, wave = t >> 6;
  const int cn = ((wave & 1) * 8 + (lane & 7)) * 8;
  const int cm = ((wave >> 1) * 8 + (lane >> 3)) * 8;
  float acc[8][8] = {};
  const float* xb = x + (size_t)m0 * NIN;
  const float* wb = We + (size_t)n0 * NIN;
  for (int k0 = 0; k0 < NIN; k0 += BK) {
#pragma unroll
    for (int i = 0; i < 2; ++i) {
      int e = t + i * 256;
      int row = e >> 2, q = e & 3;
      float4 bv = *(const float4*)(bvec + k0 + q * 4);
      float4 av = *(const float4*)(xb + (size_t)row * NIN + k0 + q * 4);
      av.x -= bv.x; av.y -= bv.y; av.z -= bv.z; av.w -= bv.w;
      As[q * 4 + 0][row] = av.x; As[q * 4 + 1][row] = av.y;
      As[q * 4 + 2][row] = av.z; As[q * 4 + 3][row] = av.w;
      float4 wv = *(const float4*)(wb + (size_t)row * NIN + k0 + q * 4);
      Bs[q * 4 + 0][row] = wv.x; Bs[q * 4 + 1][row] = wv.y;
      Bs[q * 4 + 2][row] = wv.z; Bs[q * 4 + 3][row] = wv.w;
    }
    __syncthreads();
#pragma unroll
    for (int kk = 0; kk < BK; ++kk) {
      float a0[8], b0[8];
      *(float4*)&a0[0] = *(const float4*)&As[kk][cm];
      *(float4*)&a0[4] = *(const float4*)&As[kk][cm + 4];
      *(float4*)&b0[0] = *(const float4*)&Bs[kk][cn];
      *(float4*)&b0[4] = *(const float4*)&Bs[kk][cn + 4];
#pragma unroll
      for (int i = 0; i < 8; ++i)
#pragma unroll
        for (int j = 0; j < 8; ++j)
          acc[i][j] = fmaf(a0[i], b0[j], acc[i][j]);
    }
    __syncthreads();
  }
  float bb[8];
  *(float4*)&bb[0] = *(const float4*)(be + n0 + cn);
  *(float4*)&bb[4] = *(const float4*)(be + n0 + cn + 4);
#pragma unroll
  for (int i = 0; i < 8; ++i) {
    float4 v0 = make_float4(acc[i][0] + bb[0], acc[i][1] + bb[1],
                            acc[i][2] + bb[2], acc[i][3] + bb[3]);
    float4 v1 = make_float4(acc[i][4] + bb[4], acc[i][5] + bb[5],
                            acc[i][6] + bb[6], acc[i][7] + bb[7]);
    float* orow = apre + (size_t)(m0 + cm + i) * NLAT + n0 + cn;
    *(float4*)orow = v0;
    *(float4*)(orow + 4) = v1;
  }
}

// ------------- per-row top-k select: keys live in LDS (no spill possible) ----
// Thread t owns elements 4*(t+1024*i)+q; every key scan reads only the
// thread's own uint4s (contiguous b128, conflict-free). apre/mask alias.
__global__ __launch_bounds__(SELT) void k_select7(
    const float* apre, const float* __restrict__ x,
    const float* __restrict__ bvec, const float* __restrict__ We,
    const float* __restrict__ be, const unsigned* __restrict__ dbits,
    const int* __restrict__ kptr, const int* __restrict__ akptr,
    float* __restrict__ alpha, float* mask,
    int* __restrict__ cnts, int* __restrict__ mIdxG, float* __restrict__ mValG,
    int* __restrict__ aIdxG, float* __restrict__ aValG) {
  extern __shared__ char smem[];
  uint4*    keys4   = (uint4*)(smem + OFF_KEYS);
  int*      wred    = (int*)(smem + OFF_WRED);       // [2][48]
  unsigned* wredu   = (unsigned*)(smem + OFF_WREDU); // [2][16]
  int*      ctrl    = (int*)(smem + OFF_CTRL);
  unsigned* candK   = (unsigned*)(smem + OFF_CANDK);
  int*      candI   = (int*)(smem + OFF_CANDI);
  int*      bandI   = (int*)(smem + OFF_BANDI);
  double*   bandV   = (double*)(smem + OFF_BANDV);
  unsigned char* bandSel = (unsigned char*)(smem + OFF_BANDS);

  const int t = threadIdx.x;
  const int r = blockIdx.x;
  const int lane = t & 63, wave = t >> 6;   // 16 waves

  // ---- load row -> fkey -> LDS; dead bits (1 reg) ----
  const uint4* rowp = (const uint4*)(apre + (size_t)r * NLAT);
  unsigned dm = 0;
#pragma unroll
  for (int i = 0; i < GRP; ++i) {
    int g = t + SELT * i;
    uint4 rv = rowp[g];
    uint4 kv;
    kv.x = fkey(__uint_as_float(rv.x)); kv.y = fkey(__uint_as_float(rv.y));
    kv.z = fkey(__uint_as_float(rv.z)); kv.w = fkey(__uint_as_float(rv.w));
    keys4[g] = kv;
    unsigned nb = (dbits[g >> 3] >> ((g & 7) * 4)) & 0xFu;
    dm |= nb << (4 * i);
  }
  int kmain = kptr[0]; if (kmain > MAIN_CAP) kmain = MAIN_CAP;
  int kaux  = akptr[0]; if (kaux > AUX_CAP)  kaux  = AUX_CAP;

  int par = 0, paru = 0;

  for (int pass = 0; pass < 2; ++pass) {
    int kreq, nelig;
    if (pass == 0) { kreq = kmain; nelig = NLAT; }
    else {
      // zero keys of non-dead latents (marker 0 < any finite key)
#pragma unroll
      for (int i = 0; i < GRP; ++i) {
        int g = t + SELT * i;
        unsigned nb = (dm >> (4 * i)) & 0xFu;
        if (nb != 0xFu) {
          uint4 kv = keys4[g];
          if (!(nb & 1u)) kv.x = 0u;
          if (!(nb & 2u)) kv.y = 0u;
          if (!(nb & 4u)) kv.z = 0u;
          if (!(nb & 8u)) kv.w = 0u;
          keys4[g] = kv;
        }
      }
      int pc = __popc(dm & 0xFFFFFFu);
#pragma unroll
      for (int o = 32; o; o >>= 1) pc += __shfl_xor(pc, o);
      if (lane == 0) wred[par * 48 + wave] = pc;
      __syncthreads();
      nelig = 0;
#pragma unroll
      for (int w = 0; w < 16; ++w) nelig += wred[par * 48 + w];
      par ^= 1;
      kreq = kaux;
    }
    if (kreq > nelig) kreq = nelig;
    if (kreq <= 0) {
      if (t == 0) cnts[2 * r + pass] = 0;
      continue;
    }

    // ---- block max/min of eligible keys ----
    unsigned mx = 0u, mn = 0xFFFFFFFFu;
#pragma unroll
    for (int i = 0; i < GRP; ++i) {
      uint4 kv = keys4[t + SELT * i];
      unsigned nb = (pass == 0) ? 0xFu : ((dm >> (4 * i)) & 0xFu);
      if (nb & 1u) { mx = kv.x > mx ? kv.x : mx; mn = kv.x < mn ? kv.x : mn; }
      if (nb & 2u) { mx = kv.y > mx ? kv.y : mx; mn = kv.y < mn ? kv.y : mn; }
      if (nb & 4u) { mx = kv.z > mx ? kv.z : mx; mn = kv.z < mn ? kv.z : mn; }
      if (nb & 8u) { mx = kv.w > mx ? kv.w : mx; mn = kv.w < mn ? kv.w : mn; }
    }
#pragma unroll
    for (int o = 32; o; o >>= 1) {
      unsigned om = __shfl_xor(mx, o); mx = om > mx ? om : mx;
      unsigned on = __shfl_xor(mn, o); mn = on < mn ? on : mn;
    }
    if (lane == 0) { wredu[paru * 16 + wave] = mx; wredu[(paru ^ 1) * 16 + wave] = mn; }
    __syncthreads();
    mx = 0u; mn = 0xFFFFFFFFu;
#pragma unroll
    for (int w = 0; w < 16; ++w) {
      unsigned a = wredu[paru * 16 + w], b = wredu[(paru ^ 1) * 16 + w];
      mx = a > mx ? a : mx; mn = b < mn ? b : mn;
    }
    __syncthreads();

    // ---- value-space 3-threshold probe for the k-th boundary window ----
    unsigned Tlo = mn, Thi = mx + 1u;
    int cLo = nelig, cHi = 0;
    float vlo = keyinv(mn), vhi = keyinv(mx);
    for (int it = 0; it < 24 && (cLo - cHi) > (CAND_CAP - 8); ++it) {
      float v1 = 0.75f * vlo + 0.25f * vhi;
      float v2 = 0.50f * vlo + 0.50f * vhi;
      float v3 = 0.25f * vlo + 0.75f * vhi;
      unsigned T1 = fkey(v1), T2 = fkey(v2), T3 = fkey(v3);
      if (!(T1 > Tlo && T3 < Thi && T1 <= T2 && T2 <= T3)) break;
      int c1 = 0, c2 = 0, c3 = 0;
#pragma unroll
      for (int i = 0; i < GRP; ++i) {
        uint4 kv = keys4[t + SELT * i];
        c1 += (kv.x >= T1) + (kv.y >= T1) + (kv.z >= T1) + (kv.w >= T1);
        c2 += (kv.x >= T2) + (kv.y >= T2) + (kv.z >= T2) + (kv.w >= T2);
        c3 += (kv.x >= T3) + (kv.y >= T3) + (kv.z >= T3) + (kv.w >= T3);
      }
#pragma unroll
      for (int o = 32; o; o >>= 1) {
        c1 += __shfl_xor(c1, o); c2 += __shfl_xor(c2, o); c3 += __shfl_xor(c3, o);
      }
      if (lane == 0) {
        wred[par * 48 + wave * 3 + 0] = c1;
        wred[par * 48 + wave * 3 + 1] = c2;
        wred[par * 48 + wave * 3 + 2] = c3;
      }
      __syncthreads();
      c1 = 0; c2 = 0; c3 = 0;
#pragma unroll
      for (int w = 0; w < 16; ++w) {
        c1 += wred[par * 48 + w * 3 + 0];
        c2 += wred[par * 48 + w * 3 + 1];
        c3 += wred[par * 48 + w * 3 + 2];
      }
      par ^= 1;
      if (c3 >= kreq)      { Tlo = T3; cLo = c3; vlo = v3; }
      else if (c2 >= kreq) { Tlo = T2; cLo = c2; vlo = v2; Thi = T3; cHi = c3; vhi = v3; }
      else if (c1 >= kreq) { Tlo = T1; cLo = c1; vlo = v1; Thi = T2; cHi = c2; vhi = v2; }
      else                 { Thi = T1; cHi = c1; vhi = v1; }
    }

    // ---- extract window candidates, exact-rank the k-th key ----
    if (t == 0) ctrl[0] = 0;
    __syncthreads();
#pragma unroll
    for (int i = 0; i < GRP; ++i) {
      int g = t + SELT * i;
      uint4 kv = keys4[g];
      unsigned ks[4] = {kv.x, kv.y, kv.z, kv.w};
#pragma unroll
      for (int q = 0; q < 4; ++q) {
        unsigned kk = ks[q];
        if (kk >= Tlo && kk < Thi) {
          int p = atomicAdd(&ctrl[0], 1);
          if (p < CAND_CAP) { candK[p] = kk; candI[p] = 4 * g + q; }
        }
      }
    }
    __syncthreads();
    int cc = ctrl[0]; if (cc > CAND_CAP) cc = CAND_CAP;
    int need = kreq - cHi;
    if (need < 1) need = 1;
    if (need > cc) need = cc;
    if (t < cc) {
      unsigned ki = candK[t]; int ii = candI[t];
      int rank = 0;
      for (int qq = 0; qq < cc; ++qq) {
        unsigned kq = candK[qq];
        rank += (kq > ki || (kq == ki && candI[qq] < ii)) ? 1 : 0;
      }
      if (rank == need - 1) ctrl[1] = (int)ki;
    }
    __syncthreads();

    // ---- f64 band refinement around V* ----
    float Vs = keyinv((unsigned)ctrl[1]);
    float eps = 1e-2f + 2e-3f * fabsf(Vs);
    unsigned KhiB = fkey(Vs + eps), KloB = fkey(Vs - eps);
    if (t == 0) { ctrl[2] = 0; ctrl[3] = 0; }
    __syncthreads();
    int abv = 0;
#pragma unroll
    for (int i = 0; i < GRP; ++i) {
      int g = t + SELT * i;
      uint4 kv = keys4[g];
      unsigned ks[4] = {kv.x, kv.y, kv.z, kv.w};
#pragma unroll
      for (int q = 0; q < 4; ++q) {
        unsigned kk = ks[q];
        if (kk > KhiB) ++abv;
        else if (kk >= KloB) {
          int p = atomicAdd(&ctrl[3], 1);
          if (p < BAND_CAP) bandI[p] = 4 * g + q;
        }
      }
    }
#pragma unroll
    for (int o = 32; o; o >>= 1) abv += __shfl_xor(abv, o);
    if (lane == 0) atomicAdd(&ctrl[2], abv);
    __syncthreads();
    int nAb = ctrl[2];
    int bc = ctrl[3]; if (bc > BAND_CAP) bc = BAND_CAP;
    int needB = kreq - nAb;
    if (needB < 0) needB = 0;
    if (needB > bc) needB = bc;

    // wave-per-member f64 dot: lane l covers cols l, l+64, ... (coalesced)
    {
      const float* xr = x + (size_t)r * NIN;
      for (int m = wave; m < bc; m += 16) {
        int j = bandI[m];
        const float* wr = We + (size_t)j * NIN;
        double s = 0.0;
#pragma unroll
        for (int jj = 0; jj < NIN / 64; ++jj) {
          int col = lane + 64 * jj;
          s += ((double)xr[col] - (double)bvec[col]) * (double)wr[col];
        }
#pragma unroll
        for (int o = 32; o; o >>= 1) s += __shfl_xor(s, o);
        if (lane == 0) bandV[m] = s + (double)be[j];
      }
    }
    __syncthreads();
    if (t < bc) {
      double vi = bandV[t]; int ii = bandI[t];
      double tie = fabs(vi) * 4e-8 + 1e-12;
      int rank = 0;
      for (int qq = 0; qq < bc; ++qq) {
        double d = bandV[qq] - vi;
        rank += ((fabs(d) <= tie) ? (bandI[qq] < ii) : (d > 0.0)) ? 1 : 0;
      }
      bandSel[t] = (rank < needB) ? 1 : 0;
    }
    if (t == 0) ctrl[4] = 0;
    __syncthreads();

    // ---- emit ----
    if (pass == 0) {
      float4* arow = (float4*)(alpha + (size_t)r * NLAT);
      float4* mrow = (float4*)(mask + (size_t)r * NLAT);
#pragma unroll
      for (int i = 0; i < GRP; ++i) {
        int g = t + SELT * i;
        uint4 kv = keys4[g];
        unsigned ks[4] = {kv.x, kv.y, kv.z, kv.w};
        float av[4], mv[4];
#pragma unroll
        for (int q = 0; q < 4; ++q) {
          unsigned kk = ks[q];
          int j = 4 * g + q;
          bool sel = kk > KhiB;
          if (!sel && kk >= KloB) {
            for (int m2 = 0; m2 < bc; ++m2)
              if (bandI[m2] == j) { sel = bandSel[m2] != 0; break; }
          }
          float v = keyinv(kk);
          bool nz = sel && (v != 0.0f);
          av[q] = sel ? v : 0.0f;
          mv[q] = nz ? 1.0f : 0.0f;
          if (nz) {
            int p = atomicAdd(&ctrl[4], 1);
            if (p < MAIN_CAP) { mIdxG[r * MAIN_CAP + p] = j; mValG[r * MAIN_CAP + p] = v; }
          }
        }
        arow[g] = make_float4(av[0], av[1], av[2], av[3]);
        mrow[g] = make_float4(mv[0], mv[1], mv[2], mv[3]);
      }
    } else {
#pragma unroll
      for (int i = 0; i < GRP; ++i) {
        int g = t + SELT * i;
        uint4 kv = keys4[g];
        unsigned ks[4] = {kv.x, kv.y, kv.z, kv.w};
#pragma unroll
        for (int q = 0; q < 4; ++q) {
          unsigned kk = ks[q];
          if (kk == 0u) continue;  // marker (non-dead)
          int j = 4 * g + q;
          bool sel = kk > KhiB;
          if (!sel && kk >= KloB) {
            for (int m2 = 0; m2 < bc; ++m2)
              if (bandI[m2] == j) { sel = bandSel[m2] != 0; break; }
          }
          float v = keyinv(kk);
          if (sel && v != 0.0f) {
            int p = atomicAdd(&ctrl[4], 1);
            if (p < AUX_CAP) { aIdxG[r * AUX_CAP + p] = j; aValG[r * AUX_CAP + p] = v; }
          }
        }
      }
    }
    __syncthreads();
    if (t == 0) {
      int c = ctrl[4];
      int cap = (pass == 0) ? MAIN_CAP : AUX_CAP;
      cnts[2 * r + pass] = c < cap ? c : cap;
    }
    __syncthreads();
  }
}

// ------------- decode: xhat/auxo from (idx,val) lists; no VGPR cap ----
__global__ __launch_bounds__(256) void k_decode(
    const int* __restrict__ cnts, const int* __restrict__ mIdxG,
    const float* __restrict__ mValG, const int* __restrict__ aIdxG,
    const float* __restrict__ aValG, const float* __restrict__ bvec,
    const __bf16* __restrict__ Wt, const float* __restrict__ Wd,
    float* __restrict__ xhat, float* __restrict__ auxo) {
  const int r = blockIdx.x, t = threadIdx.x;
  __shared__ int sMi[MAIN_CAP];
  __shared__ float sMv[MAIN_CAP];
  __shared__ int sAi[AUX_CAP];
  __shared__ float sAv[AUX_CAP];
  int kc = cnts[2 * r], ac = cnts[2 * r + 1];
  if (t < MAIN_CAP && t < kc) { sMi[t] = mIdxG[r * MAIN_CAP + t]; sMv[t] = mValG[r * MAIN_CAP + t]; }
  for (int i = t; i < ac; i += 256) { sAi[i] = aIdxG[r * AUX_CAP + i]; sAv[i] = aValG[r * AUX_CAP + i]; }
  __syncthreads();

  float o0 = 0.f, o1 = 0.f, o2 = 0.f;   // cols t, t+256, t+512
  float a0 = 0.f, a1 = 0.f, a2 = 0.f;
  if (Wt) {
    int i = 0;
    for (; i + 4 <= kc; i += 4) {
      int i0 = sMi[i], i1 = sMi[i + 1], i2 = sMi[i + 2], i3 = sMi[i + 3];
      float v0 = sMv[i], v1 = sMv[i + 1], v2 = sMv[i + 2], v3 = sMv[i + 3];
      const __bf16* p0 = Wt + (size_t)i0 * NIN;
      const __bf16* p1 = Wt + (size_t)i1 * NIN;
      const __bf16* p2 = Wt + (size_t)i2 * NIN;
      const __bf16* p3 = Wt + (size_t)i3 * NIN;
      float w00 = p0[t], w01 = p0[t + 256], w02 = p0[t + 512];
      float w10 = p1[t], w11 = p1[t + 256], w12 = p1[t + 512];
      float w20 = p2[t], w21 = p2[t + 256], w22 = p2[t + 512];
      float w30 = p3[t], w31 = p3[t + 256], w32 = p3[t + 512];
      o0 = fmaf(v0, w00, o0); o1 = fmaf(v0, w01, o1); o2 = fmaf(v0, w02, o2);
      o0 = fmaf(v1, w10, o0); o1 = fmaf(v1, w11, o1); o2 = fmaf(v1, w12, o2);
      o0 = fmaf(v2, w20, o0); o1 = fmaf(v2, w21, o1); o2 = fmaf(v2, w22, o2);
      o0 = fmaf(v3, w30, o0); o1 = fmaf(v3, w31, o1); o2 = fmaf(v3, w32, o2);
    }
    for (; i < kc; ++i) {
      const __bf16* p = Wt + (size_t)sMi[i] * NIN;
      float v = sMv[i];
      o0 = fmaf(v, (float)p[t], o0);
      o1 = fmaf(v, (float)p[t + 256], o1);
      o2 = fmaf(v, (float)p[t + 512], o2);
    }
    i = 0;
    for (; i + 4 <= ac; i += 4) {
      int i0 = sAi[i], i1 = sAi[i + 1], i2 = sAi[i + 2], i3 = sAi[i + 3];
      float v0 = sAv[i], v1 = sAv[i + 1], v2 = sAv[i + 2], v3 = sAv[i + 3];
      const __bf16* p0 = Wt + (size_t)i0 * NIN;
      const __bf16* p1 = Wt + (size_t)i1 * NIN;
      const __bf16* p2 = Wt + (size_t)i2 * NIN;
      const __bf16* p3 = Wt + (size_t)i3 * NIN;
      float w00 = p0[t], w01 = p0[t + 256], w02 = p0[t + 512];
      float w10 = p1[t], w11 = p1[t + 256], w12 = p1[t + 512];
      float w20 = p2[t], w21 = p2[t + 256], w22 = p2[t + 512];
      float w30 = p3[t], w31 = p3[t + 256], w32 = p3[t + 512];
      a0 = fmaf(v0, w00, a0); a1 = fmaf(v0, w01, a1); a2 = fmaf(v0, w02, a2);
      a0 = fmaf(v1, w10, a0); a1 = fmaf(v1, w11, a1); a2 = fmaf(v1, w12, a2);
      a0 = fmaf(v2, w20, a0); a1 = fmaf(v2, w21, a1); a2 = fmaf(v2, w22, a2);
      a0 = fmaf(v3, w30, a0); a1 = fmaf(v3, w31, a1); a2 = fmaf(v3, w32, a2);
    }
    for (; i < ac; ++i) {
      const __bf16* p = Wt + (size_t)sAi[i] * NIN;
      float v = sAv[i];
      a0 = fmaf(v, (float)p[t], a0);
      a1 = fmaf(v, (float)p[t + 256], a1);
      a2 = fmaf(v, (float)p[t + 512], a2);
    }
  } else {  // fallback: strided gather from W_dec [NIN][NLAT]
    for (int i = 0; i < kc; ++i) {
      float v = sMv[i]; int ix = sMi[i];
      o0 = fmaf(v, Wd[(size_t)t * NLAT + ix], o0);
      o1 = fmaf(v, Wd[(size_t)(t + 256) * NLAT + ix], o1);
      o2 = fmaf(v, Wd[(size_t)(t + 512) * NLAT + ix], o2);
    }
    for (int i = 0; i < ac; ++i) {
      float v = sAv[i]; int ix = sAi[i];
      a0 = fmaf(v, Wd[(size_t)t * NLAT + ix], a0);
      a1 = fmaf(v, Wd[(size_t)(t + 256) * NLAT + ix], a1);
      a2 = fmaf(v, Wd[(size_t)(t + 512) * NLAT + ix], a2);
    }
  }
  float b0 = bvec[t], b1 = bvec[t + 256], b2 = bvec[t + 512];
  xhat[(size_t)r * NIN + t] = o0 + b0;
  xhat[(size_t)r * NIN + t + 256] = o1 + b1;
  xhat[(size_t)r * NIN + t + 512] = o2 + b2;
  auxo[(size_t)r * NIN + t] = a0 + b0;
  auxo[(size_t)r * NIN + t + 256] = a1 + b1;
  auxo[(size_t)r * NIN + t + 512] = a2 + b2;
}

extern "C" void kernel_launch(void* const* d_in, const int* in_sizes, int n_in,
                              void* d_out, int out_size, void* d_ws, size_t ws_size,
                              hipStream_t stream) {
  const float* x  = (const float*)d_in[0];
  const float* bv = (const float*)d_in[1];
  const float* We = (const float*)d_in[2];
  const float* be = (const float*)d_in[3];
  const float* Wd = (const float*)d_in[4];
  const int* miss = (const int*)d_in[5];
  const int* kp   = (const int*)d_in[6];
  const int* akp  = (const int*)d_in[7];

  float* out   = (float*)d_out;
  float* xhat  = out;                          // [4096 x 768]
  float* alpha = out + (size_t)3145728;        // [4096 x 24576]
  float* apre  = out + (size_t)103809024;      // fired_mask region; alpha_pre scratch
  float* auxo  = out + (size_t)204472320;      // [4096 x 768]

  // ws layout: dbits 64K | cnts 64K | mIdx 1M | mVal 1M | aIdx 16M | aVal 16M
  //            | Wt bf16 36M | A2 12M | B2 72M   (~154 MB total)
  char* wsb = (char*)d_ws;
  unsigned* dbits = (unsigned*)wsb;
  int*   cnts  = (int*)(wsb + 65536);
  int*   mIdxG = (int*)(wsb + 131072);
  float* mValG = (float*)(wsb + 131072 + (size_t)NB * MAIN_CAP * 4);
  int*   aIdxG = (int*)(wsb + 131072 + (size_t)NB * MAIN_CAP * 8);
  float* aValG = (float*)(wsb + 131072 + (size_t)NB * MAIN_CAP * 8 + (size_t)NB * AUX_CAP * 4);
  size_t offWt = 131072 + (size_t)NB * MAIN_CAP * 8 + (size_t)NB * AUX_CAP * 8;
  size_t offA2 = offWt + (size_t)NLAT * NIN * 2;
  size_t offB2 = offA2 + (size_t)NB * K2 * 2;
  size_t needFull = offB2 + (size_t)NLAT * K2 * 2;
  bool haveWt   = ws_size >= offA2;
  bool haveFull = ws_size >= needFull;
  __bf16* Wt = haveWt ? (__bf16*)(wsb + offWt) : nullptr;
  __bf16* A2 = (__bf16*)(wsb + offA2);
  __bf16* B2 = (__bf16*)(wsb + offB2);

  k_deadbits<<<96, 256, 0, stream>>>(miss, dbits);
  if (haveFull) {
    k_pack_a<<<dim3(32, KT2), 256, 0, stream>>>(x, bv, A2);
    k_pack_b<<<dim3(192, KT2), 256, 0, stream>>>(We, B2);
  }
  if (haveWt)
    k_transpose<<<dim3(NLAT / 32, NIN / 32), dim3(32, 8), 0, stream>>>(Wd, Wt);

  if (haveFull)
    k_gemm_bf16<<<dim3(32, 192), 256, 0, stream>>>(A2, B2, be, apre);
  else
    k_encgemm_f32<<<dim3(NB / BM, NLAT / BN), 256, 0, stream>>>(x, bv, We, be, apre);

  k_select7<<<NB, SELT, SMEM_SEL, stream>>>(apre, x, bv, We, be, dbits, kp, akp,
                                            alpha, apre, cnts, mIdxG, mValG,
                                            aIdxG, aValG);
  k_decode<<<NB, 256, 0, stream>>>(cnts, mIdxG, mValG, aIdxG, aValG, bv,
                                   Wt, Wd, xhat, auxo);
}

// Round 9
// 2499.740 us; speedup vs baseline: 3.1375x; 1.1067x over previous
//
#include <hip/hip_runtime.h>
#include <math.h>

#define NB   4096
#define NIN  768
#define NLAT 24576
#define K2   1536   // [Ah|Al] x [Bh|Bh]
#define KT2  24     // K2/64

// f32 fallback GEMM tiling
#define BM 128
#define BN 128
#define BK 16
#define LDT 132

#define CAND_CAP 160
#define BAND_CAP 160
#define MAIN_CAP 64
#define AUX_CAP  1024
#define SELT     1024
#define GRP      6      // uint4 groups per thread (24 elems)

// dynamic LDS layout for k_select8
#define OFF_KEYS   0                 // uint[24576] = 98304
#define OFF_REDI   98304             // int[48]
#define OFF_REDF   98496             // float[16][8]
#define OFF_CTRL   99008             // int[24] (ctrlF aliases)
#define OFF_CANDK  99104             // unsigned[CAND_CAP]
#define OFF_CANDI  99744             // int[CAND_CAP]
#define OFF_BANDI  100384            // int[BAND_CAP]
#define OFF_BANDV  101024            // double[BAND_CAP] (8B aligned)
#define OFF_BANDS  102304            // uchar[BAND_CAP]
#define SMEM_SEL   102464

typedef __bf16 bf16x8 __attribute__((ext_vector_type(8)));
typedef float  f32x4  __attribute__((ext_vector_type(4)));

__device__ __forceinline__ unsigned fkey(float f) {
  unsigned u = __float_as_uint(f);
  return u ^ ((unsigned)((int)u >> 31) | 0x80000000u);  // monotone total order
}
__device__ __forceinline__ float keyinv(unsigned u) {
  unsigned s = (u & 0x80000000u) ? (u ^ 0x80000000u) : ~u;
  return __uint_as_float(s);
}
// upper-tail inverse normal (Hastings approx): count_frac_above = p -> z
__device__ __forceinline__ float zup(float p) {
  p = fminf(fmaxf(p, 1e-7f), 0.5f);
  float t = sqrtf(-2.0f * logf(p));
  return t - (2.30753f + 0.27061f * t) / (1.0f + 0.99229f * t + 0.04481f * t * t);
}

#define GLOAD16(g, l) __builtin_amdgcn_global_load_lds( \
    (const __attribute__((address_space(1))) unsigned int*)(g), \
    (__attribute__((address_space(3))) unsigned int*)(l), 16, 0, 0)

// ---------------- dead bitset: bit j = (miss[j] >= 1) ----------------
__global__ __launch_bounds__(256) void k_deadbits(const int* __restrict__ miss,
                                                  unsigned* __restrict__ bits) {
  int j = blockIdx.x * 256 + threadIdx.x;
  unsigned long long b = __ballot(miss[j] >= 1);
  if ((threadIdx.x & 63) == 0) {
    int w = j >> 5;
    bits[w] = (unsigned)b;
    bits[w + 1] = (unsigned)(b >> 32);
  }
}

// ---------------- W_dec [NIN][NLAT] -> Wt [NLAT][NIN] (bf16) ----------------
__global__ __launch_bounds__(256) void k_transpose(const float* __restrict__ src,
                                                   __bf16* __restrict__ dst) {
  __shared__ float tile[32][33];
  int bx = blockIdx.x * 32;  // NLAT
  int by = blockIdx.y * 32;  // NIN
  int tx = threadIdx.x, ty = threadIdx.y;
  for (int i = ty; i < 32; i += 8)
    tile[i][tx] = src[(size_t)(by + i) * NLAT + bx + tx];
  __syncthreads();
  for (int i = ty; i < 32; i += 8)
    dst[(size_t)(bx + i) * NIN + by + tx] = (__bf16)tile[tx][i];
}

// ---- pack (x-b) into A2 tiles [mt][kt][128][64], pre-swizzled LDS image ----
__global__ __launch_bounds__(256) void k_pack_a(const float* __restrict__ x,
    const float* __restrict__ bvec, __bf16* __restrict__ A2) {
  const int mt = blockIdx.x, kt = blockIdx.y, t = threadIdx.x;
  __bf16* out = A2 + (((size_t)mt * KT2 + kt) << 13);
#pragma unroll
  for (int i = 0; i < 32; ++i) {
    int idx = i * 256 + t;
    int r = idx >> 6, c2 = idx & 63;
    int kk = c2 ^ ((r & 7) << 3);
    int kg = kt * 64 + kk;
    int k = kg >= 768 ? kg - 768 : kg;
    bool lo = (kg >= 768);                            // A = [Ah | Al]
    float v = x[(size_t)(mt * 128 + r) * NIN + k] - bvec[k];
    __bf16 h = (__bf16)v;
    out[idx] = lo ? (__bf16)(v - (float)h) : h;
  }
}

__global__ __launch_bounds__(256) void k_pack_b(const float* __restrict__ We,
    __bf16* __restrict__ B2) {
  const int nt = blockIdx.x, kt = blockIdx.y, t = threadIdx.x;
  __bf16* out = B2 + (((size_t)nt * KT2 + kt) << 13);
#pragma unroll
  for (int i = 0; i < 32; ++i) {
    int idx = i * 256 + t;
    int r = idx >> 6, c2 = idx & 63;
    int kk = c2 ^ ((r & 7) << 3);
    int kg = kt * 64 + kk;
    int k = kg >= 768 ? kg - 768 : kg;                // B = [Bh | Bh]
    float v = We[(size_t)(nt * 128 + r) * NIN + k];
    out[idx] = (__bf16)v;
  }
}

// ---------------- bf16 MFMA GEMM: apre = A2 @ B2^T + be ----------------
__global__ __launch_bounds__(256) void k_gemm_bf16(
    const __bf16* __restrict__ A2, const __bf16* __restrict__ B2,
    const float* __restrict__ be, float* __restrict__ apre) {
  __shared__ char sA[16384];
  __shared__ char sB[16384];
  const int t = threadIdx.x;
  const int lane = t & 63, wave = t >> 6;
  const int mt = blockIdx.x, nt = blockIdx.y;
  const int wm = wave >> 1, wn = wave & 1;

  int aoff[4][2], boff[4][2];
#pragma unroll
  for (int f = 0; f < 4; ++f) {
    int ra = wm * 64 + f * 16 + (lane & 15);
    int rb = wn * 64 + f * 16 + (lane & 15);
#pragma unroll
    for (int kk = 0; kk < 2; ++kk) {
      int c = kk * 64 + (lane >> 4) * 16;
      aoff[f][kk] = ra * 128 + (c ^ ((ra & 7) << 4));
      boff[f][kk] = rb * 128 + (c ^ ((rb & 7) << 4));
    }
  }
  f32x4 acc[4][4] = {};
  const char* gA = (const char*)(A2 + (((size_t)mt * KT2) << 13));
  const char* gB = (const char*)(B2 + (((size_t)nt * KT2) << 13));
  for (int kt = 0; kt < KT2; ++kt) {
    const char* tA = gA + ((size_t)kt << 14);
    const char* tB = gB + ((size_t)kt << 14);
#pragma unroll
    for (int i = 0; i < 4; ++i) {
      int chunk = (i * 4 + wave) * 1024;
      GLOAD16(tA + chunk + lane * 16, sA + chunk);
      GLOAD16(tB + chunk + lane * 16, sB + chunk);
    }
    __syncthreads();
#pragma unroll
    for (int kk = 0; kk < 2; ++kk) {
      bf16x8 a[4], b[4];
#pragma unroll
      for (int f = 0; f < 4; ++f) {
        a[f] = *(const bf16x8*)(sA + aoff[f][kk]);
        b[f] = *(const bf16x8*)(sB + boff[f][kk]);
      }
#pragma unroll
      for (int mi = 0; mi < 4; ++mi)
#pragma unroll
        for (int ni = 0; ni < 4; ++ni)
          acc[mi][ni] = __builtin_amdgcn_mfma_f32_16x16x32_bf16(a[mi], b[ni], acc[mi][ni], 0, 0, 0);
    }
    __syncthreads();
  }
  const int m0 = mt * 128 + wm * 64, n0 = nt * 128 + wn * 64;
#pragma unroll
  for (int ni = 0; ni < 4; ++ni) {
    int n = n0 + ni * 16 + (lane & 15);
    float bb = be[n];
#pragma unroll
    for (int mi = 0; mi < 4; ++mi) {
      int mbase = m0 + mi * 16 + (lane >> 4) * 4;
#pragma unroll
      for (int q = 0; q < 4; ++q)
        apre[(size_t)(mbase + q) * NLAT + n] = acc[mi][ni][q] + bb;
    }
  }
}

// ---------------- f32 fallback GEMM ----------------
__global__ __launch_bounds__(256) void k_encgemm_f32(
    const float* __restrict__ x, const float* __restrict__ bvec,
    const float* __restrict__ We, const float* __restrict__ be,
    float* __restrict__ apre) {
  __shared__ float As[BK][LDT];
  __shared__ float Bs[BK][LDT];
  const int t = threadIdx.x;
  const int m0 = blockIdx.x * BM;
  const int n0 = blockIdx.y * BN;
  const int lane = t & 63, wave = t >> 6;
  const int cn = ((wave & 1) * 8 + (lane & 7)) * 8;
  const int cm = ((wave >> 1) * 8 + (lane >> 3)) * 8;
  float acc[8][8] = {};
  const float* xb = x + (size_t)m0 * NIN;
  const float* wb = We + (size_t)n0 * NIN;
  for (int k0 = 0; k0 < NIN; k0 += BK) {
#pragma unroll
    for (int i = 0; i < 2; ++i) {
      int e = t + i * 256;
      int row = e >> 2, q = e & 3;
      float4 bv = *(const float4*)(bvec + k0 + q * 4);
      float4 av = *(const float4*)(xb + (size_t)row * NIN + k0 + q * 4);
      av.x -= bv.x; av.y -= bv.y; av.z -= bv.z; av.w -= bv.w;
      As[q * 4 + 0][row] = av.x; As[q * 4 + 1][row] = av.y;
      As[q * 4 + 2][row] = av.z; As[q * 4 + 3][row] = av.w;
      float4 wv = *(const float4*)(wb + (size_t)row * NIN + k0 + q * 4);
      Bs[q * 4 + 0][row] = wv.x; Bs[q * 4 + 1][row] = wv.y;
      Bs[q * 4 + 2][row] = wv.z; Bs[q * 4 + 3][row] = wv.w;
    }
    __syncthreads();
#pragma unroll
    for (int kk = 0; kk < BK; ++kk) {
      float a0[8], b0[8];
      *(float4*)&a0[0] = *(const float4*)&As[kk][cm];
      *(float4*)&a0[4] = *(const float4*)&As[kk][cm + 4];
      *(float4*)&b0[0] = *(const float4*)&Bs[kk][cn];
      *(float4*)&b0[4] = *(const float4*)&Bs[kk][cn + 4];
#pragma unroll
      for (int i = 0; i < 8; ++i)
#pragma unroll
        for (int j = 0; j < 8; ++j)
          acc[i][j] = fmaf(a0[i], b0[j], acc[i][j]);
    }
    __syncthreads();
  }
  float bb[8];
  *(float4*)&bb[0] = *(const float4*)(be + n0 + cn);
  *(float4*)&bb[4] = *(const float4*)(be + n0 + cn + 4);
#pragma unroll
  for (int i = 0; i < 8; ++i) {
    float4 v0 = make_float4(acc[i][0] + bb[0], acc[i][1] + bb[1],
                            acc[i][2] + bb[2], acc[i][3] + bb[3]);
    float4 v1 = make_float4(acc[i][4] + bb[4], acc[i][5] + bb[5],
                            acc[i][6] + bb[6], acc[i][7] + bb[7]);
    float* orow = apre + (size_t)(m0 + cm + i) * NLAT + n0 + cn;
    *(float4*)orow = v0;
    *(float4*)(orow + 4) = v1;
  }
}

// ------------- per-row top-k select: LDS keys + analytic probe seeding ----
__global__ __launch_bounds__(SELT) void k_select8(
    const float* apre, const float* __restrict__ x,
    const float* __restrict__ bvec, const float* __restrict__ We,
    const float* __restrict__ be, const unsigned* __restrict__ dbits,
    const int* __restrict__ kptr, const int* __restrict__ akptr,
    float* __restrict__ alpha, float* mask,
    int* __restrict__ cnts, int* __restrict__ mIdxG, float* __restrict__ mValG,
    int* __restrict__ aIdxG, float* __restrict__ aValG) {
  extern __shared__ char smem[];
  uint4*    keys4 = (uint4*)(smem + OFF_KEYS);
  unsigned* keys1 = (unsigned*)(smem + OFF_KEYS);
  int*      redI  = (int*)(smem + OFF_REDI);
  float*    redF  = (float*)(smem + OFF_REDF);
  int*      ctrl  = (int*)(smem + OFF_CTRL);
  float*    ctrlF = (float*)(smem + OFF_CTRL);
  unsigned* candK = (unsigned*)(smem + OFF_CANDK);
  int*      candI = (int*)(smem + OFF_CANDI);
  int*      bandI = (int*)(smem + OFF_BANDI);
  double*   bandV = (double*)(smem + OFF_BANDV);
  unsigned char* bandSel = (unsigned char*)(smem + OFF_BANDS);

  const int t = threadIdx.x;
  const int r = blockIdx.x;
  const int lane = t & 63, wave = t >> 6;   // 16 waves

  // ---- load row -> fkey -> LDS; fused stats (mu, sigma, min/max, dead) ----
  const uint4* rowp = (const uint4*)(apre + (size_t)r * NLAT);
  unsigned dm = 0;
  float s1 = 0.f, s2 = 0.f;
  float vmxA = -INFINITY, vmnA = INFINITY, vmxD = -INFINITY, vmnD = INFINITY;
#pragma unroll
  for (int i = 0; i < GRP; ++i) {
    int g = t + SELT * i;
    uint4 rv = rowp[g];
    unsigned nb = (dbits[g >> 3] >> ((g & 7) * 4)) & 0xFu;
    dm |= nb << (4 * i);
    float vs[4] = {__uint_as_float(rv.x), __uint_as_float(rv.y),
                   __uint_as_float(rv.z), __uint_as_float(rv.w)};
    uint4 kv;
    kv.x = fkey(vs[0]); kv.y = fkey(vs[1]); kv.z = fkey(vs[2]); kv.w = fkey(vs[3]);
    keys4[g] = kv;
#pragma unroll
    for (int q = 0; q < 4; ++q) {
      float v = vs[q];
      s1 += v; s2 += v * v;
      vmxA = fmaxf(vmxA, v); vmnA = fminf(vmnA, v);
      if ((nb >> q) & 1u) { vmxD = fmaxf(vmxD, v); vmnD = fminf(vmnD, v); }
    }
  }
  int nd = __popc(dm & 0xFFFFFFu);
#pragma unroll
  for (int o = 32; o; o >>= 1) {
    s1 += __shfl_xor(s1, o); s2 += __shfl_xor(s2, o);
    vmxA = fmaxf(vmxA, __shfl_xor(vmxA, o)); vmnA = fminf(vmnA, __shfl_xor(vmnA, o));
    vmxD = fmaxf(vmxD, __shfl_xor(vmxD, o)); vmnD = fminf(vmnD, __shfl_xor(vmnD, o));
    nd += __shfl_xor(nd, o);
  }
  if (lane == 0) {
    float* rf = redF + wave * 8;
    rf[0] = s1; rf[1] = s2; rf[2] = vmxA; rf[3] = vmnA; rf[4] = vmxD; rf[5] = vmnD;
    redI[wave] = nd;
  }
  __syncthreads();
  if (wave == 0) {
    float a0 = 0.f, a1 = 0.f, a2 = -INFINITY, a3 = INFINITY, a4 = -INFINITY, a5 = INFINITY;
    int a6 = 0;
    if (lane < 16) {
      const float* rf = redF + lane * 8;
      a0 = rf[0]; a1 = rf[1]; a2 = rf[2]; a3 = rf[3]; a4 = rf[4]; a5 = rf[5];
      a6 = redI[lane];
    }
#pragma unroll
    for (int o = 32; o; o >>= 1) {
      a0 += __shfl_xor(a0, o); a1 += __shfl_xor(a1, o);
      a2 = fmaxf(a2, __shfl_xor(a2, o)); a3 = fminf(a3, __shfl_xor(a3, o));
      a4 = fmaxf(a4, __shfl_xor(a4, o)); a5 = fminf(a5, __shfl_xor(a5, o));
      a6 += __shfl_xor(a6, o);
    }
    if (lane == 0) {
      float mu = a0 / (float)NLAT;
      float var = fmaxf(a1 / (float)NLAT - mu * mu, 1e-20f);
      ctrlF[16] = mu; ctrlF[17] = sqrtf(var);
      ctrlF[18] = a3; ctrlF[19] = a2;   // vmnA, vmxA
      ctrlF[20] = a5; ctrlF[21] = a4;   // vmnD, vmxD
      ctrl[22] = a6;                    // ndead
    }
  }
  __syncthreads();

  int kmain = kptr[0]; if (kmain > MAIN_CAP) kmain = MAIN_CAP;
  int kaux  = akptr[0]; if (kaux > AUX_CAP)  kaux  = AUX_CAP;
  const float mu = ctrlF[16], sg = ctrlF[17];
  const int ndead = ctrl[22];

  for (int pass = 0; pass < 2; ++pass) {
    const bool isAux = (pass == 1);
    int nelig = isAux ? ndead : NLAT;
    int kreq  = isAux ? kaux : kmain;
    if (kreq > nelig) kreq = nelig;
    if (kreq <= 0) {
      if (t == 0) cnts[2 * r + pass] = 0;
      continue;
    }
    unsigned Tlo = fkey(isAux ? ctrlF[20] : ctrlF[18]);
    unsigned Thi = fkey(isAux ? ctrlF[21] : ctrlF[19]) + 1u;
    int cLo = nelig, cHi = 0;

    // ---- probe: analytic seed (iter 0) + geometric refinement ----
    for (int it = 0; it < 16 && (cLo - cHi) > (CAND_CAP - 8); ++it) {
      unsigned T1, T2, T3;
      if (it == 0) {
        float fn = (float)nelig;
        float v1 = mu + sg * zup(4.f * kreq / fn);
        float v2 = mu + sg * zup((float)kreq / fn);
        float v3 = mu + sg * zup(0.25f * kreq / fn);
        T1 = fkey(v1); T2 = fkey(v2); T3 = fkey(v3);
        unsigned lo1 = Tlo + 1u, hi1 = Thi - 1u;
        T1 = T1 < lo1 ? lo1 : (T1 > hi1 ? hi1 : T1);
        T2 = T2 < T1 ? T1 : (T2 > hi1 ? hi1 : T2);
        T3 = T3 < T2 ? T2 : (T3 > hi1 ? hi1 : T3);
      } else {
        float vlo = keyinv(Tlo), vhi = keyinv(Thi);
        T1 = fkey(0.75f * vlo + 0.25f * vhi);
        T2 = fkey(0.50f * vlo + 0.50f * vhi);
        T3 = fkey(0.25f * vlo + 0.75f * vhi);
        if (!(T1 > Tlo && T3 < Thi && T1 <= T2 && T2 <= T3)) break;
      }
      int c1 = 0, c2 = 0, c3 = 0;
#pragma unroll
      for (int i = 0; i < GRP; ++i) {
        uint4 kv = keys4[t + SELT * i];
        unsigned nb = isAux ? ((dm >> (4 * i)) & 0xFu) : 0xFu;
        unsigned ks[4] = {kv.x, kv.y, kv.z, kv.w};
#pragma unroll
        for (int q = 0; q < 4; ++q) {
          if ((nb >> q) & 1u) {
            unsigned kk = ks[q];
            c1 += (kk >= T1); c2 += (kk >= T2); c3 += (kk >= T3);
          }
        }
      }
#pragma unroll
      for (int o = 32; o; o >>= 1) {
        c1 += __shfl_xor(c1, o); c2 += __shfl_xor(c2, o); c3 += __shfl_xor(c3, o);
      }
      if (lane == 0) { redI[wave] = c1; redI[16 + wave] = c2; redI[32 + wave] = c3; }
      __syncthreads();
      if (wave == 0) {
        int a = (lane < 16) ? redI[lane] : 0;
        int b = (lane < 16) ? redI[16 + lane] : 0;
        int c = (lane < 16) ? redI[32 + lane] : 0;
#pragma unroll
        for (int o = 32; o; o >>= 1) {
          a += __shfl_xor(a, o); b += __shfl_xor(b, o); c += __shfl_xor(c, o);
        }
        if (lane == 0) { ctrl[8] = a; ctrl[9] = b; ctrl[10] = c; }
      }
      __syncthreads();
      c1 = ctrl[8]; c2 = ctrl[9]; c3 = ctrl[10];
      if (c3 >= kreq)      { Tlo = T3; cLo = c3; }
      else if (c2 >= kreq) { Tlo = T2; cLo = c2; Thi = T3; cHi = c3; }
      else if (c1 >= kreq) { Tlo = T1; cLo = c1; Thi = T2; cHi = c2; }
      else                 { Thi = T1; cHi = c1; }
      __syncthreads();
    }

    // ---- extract window candidates, exact-rank the k-th key ----
    if (t == 0) ctrl[0] = 0;
    __syncthreads();
#pragma unroll
    for (int i = 0; i < GRP; ++i) {
      int g = t + SELT * i;
      uint4 kv = keys4[g];
      unsigned nb = isAux ? ((dm >> (4 * i)) & 0xFu) : 0xFu;
      unsigned ks[4] = {kv.x, kv.y, kv.z, kv.w};
#pragma unroll
      for (int q = 0; q < 4; ++q) {
        unsigned kk = ks[q];
        if (((nb >> q) & 1u) && kk >= Tlo && kk < Thi) {
          int p = atomicAdd(&ctrl[0], 1);
          if (p < CAND_CAP) { candK[p] = kk; candI[p] = 4 * g + q; }
        }
      }
    }
    __syncthreads();
    int cc = ctrl[0]; if (cc > CAND_CAP) cc = CAND_CAP;
    int need = kreq - cHi;
    if (need < 1) need = 1;
    if (need > cc) need = cc;
    if (t < cc) {
      unsigned ki = candK[t]; int ii = candI[t];
      int rank = 0;
      for (int qq = 0; qq < cc; ++qq) {
        unsigned kq = candK[qq];
        rank += (kq > ki || (kq == ki && candI[qq] < ii)) ? 1 : 0;
      }
      if (rank == need - 1) ctrl[1] = (int)ki;
    }
    __syncthreads();

    // ---- f64 band refinement around V* ----
    float Vs = keyinv((unsigned)ctrl[1]);
    float eps = 1e-2f + 2e-3f * fabsf(Vs);
    unsigned KhiB = fkey(Vs + eps), KloB = fkey(Vs - eps);
    if (t == 0) { ctrl[2] = 0; ctrl[3] = 0; }
    __syncthreads();
    int abv = 0;
#pragma unroll
    for (int i = 0; i < GRP; ++i) {
      int g = t + SELT * i;
      uint4 kv = keys4[g];
      unsigned nb = isAux ? ((dm >> (4 * i)) & 0xFu) : 0xFu;
      unsigned ks[4] = {kv.x, kv.y, kv.z, kv.w};
#pragma unroll
      for (int q = 0; q < 4; ++q) {
        if (!((nb >> q) & 1u)) continue;
        unsigned kk = ks[q];
        if (kk > KhiB) ++abv;
        else if (kk >= KloB) {
          int p = atomicAdd(&ctrl[3], 1);
          if (p < BAND_CAP) bandI[p] = 4 * g + q;
        }
      }
    }
#pragma unroll
    for (int o = 32; o; o >>= 1) abv += __shfl_xor(abv, o);
    if (lane == 0) atomicAdd(&ctrl[2], abv);
    __syncthreads();
    int nAb = ctrl[2];
    int bc = ctrl[3]; if (bc > BAND_CAP) bc = BAND_CAP;
    int needB = kreq - nAb;
    if (needB < 0) needB = 0;
    if (needB > bc) needB = bc;

    // wave-per-member f64 dot; x-b hoisted to 12 scoped regs (coalesced)
    {
      const float* xr = x + (size_t)r * NIN;
      float xb[NIN / 64];
#pragma unroll
      for (int jj = 0; jj < NIN / 64; ++jj) {
        int col = lane + 64 * jj;
        xb[jj] = xr[col] - bvec[col];
      }
      for (int m = wave; m < bc; m += 16) {
        int j = bandI[m];
        const float* wr = We + (size_t)j * NIN;
        double s = 0.0;
#pragma unroll
        for (int jj = 0; jj < NIN / 64; ++jj)
          s += (double)xb[jj] * (double)wr[lane + 64 * jj];
#pragma unroll
        for (int o = 32; o; o >>= 1) s += __shfl_xor(s, o);
        if (lane == 0) bandV[m] = s + (double)be[j];
      }
    }
    __syncthreads();
    if (t < bc) {
      double vi = bandV[t]; int ii = bandI[t];
      double tie = fabs(vi) * 4e-8 + 1e-12;
      int rank = 0;
      for (int qq = 0; qq < bc; ++qq) {
        double d = bandV[qq] - vi;
        rank += ((fabs(d) <= tie) ? (bandI[qq] < ii) : (d > 0.0)) ? 1 : 0;
      }
      bandSel[t] = (rank < needB) ? 1 : 0;
    }
    if (t == 0) ctrl[4] = 0;
    __syncthreads();

    // ---- emit ----
    if (pass == 0) {
      float4* arow = (float4*)(alpha + (size_t)r * NLAT);
      float4* mrow = (float4*)(mask + (size_t)r * NLAT);
#pragma unroll
      for (int i = 0; i < GRP; ++i) {
        int g = t + SELT * i;
        uint4 kv = keys4[g];
        unsigned ks[4] = {kv.x, kv.y, kv.z, kv.w};
        float av[4], mv[4];
#pragma unroll
        for (int q = 0; q < 4; ++q) {
          unsigned kk = ks[q];
          int j = 4 * g + q;
          bool sel = kk > KhiB;
          if (!sel && kk >= KloB) {
            for (int m2 = 0; m2 < bc; ++m2)
              if (bandI[m2] == j) { sel = bandSel[m2] != 0; break; }
          }
          float v = keyinv(kk);
          bool nz = sel && (v != 0.0f);
          av[q] = sel ? v : 0.0f;
          mv[q] = nz ? 1.0f : 0.0f;
          if (nz) {
            int p = atomicAdd(&ctrl[4], 1);
            if (p < MAIN_CAP) { mIdxG[r * MAIN_CAP + p] = j; mValG[r * MAIN_CAP + p] = v; }
          }
        }
        arow[g] = make_float4(av[0], av[1], av[2], av[3]);
        mrow[g] = make_float4(mv[0], mv[1], mv[2], mv[3]);
      }
    } else {
#pragma unroll
      for (int i = 0; i < GRP; ++i) {
        int g = t + SELT * i;
        uint4 kv = keys4[g];
        unsigned nb = (dm >> (4 * i)) & 0xFu;
        unsigned ks[4] = {kv.x, kv.y, kv.z, kv.w};
#pragma unroll
        for (int q = 0; q < 4; ++q) {
          if (!((nb >> q) & 1u)) continue;
          unsigned kk = ks[q];
          int j = 4 * g + q;
          bool sel = kk > KhiB;
          if (!sel && kk >= KloB) {
            for (int m2 = 0; m2 < bc; ++m2)
              if (bandI[m2] == j) { sel = bandSel[m2] != 0; break; }
          }
          float v = keyinv(kk);
          if (sel && v != 0.0f) {
            int p = atomicAdd(&ctrl[4], 1);
            if (p < AUX_CAP) { aIdxG[r * AUX_CAP + p] = j; aValG[r * AUX_CAP + p] = v; }
          }
        }
      }
    }
    __syncthreads();
    if (t == 0) {
      int c = ctrl[4];
      int cap = (pass == 0) ? MAIN_CAP : AUX_CAP;
      cnts[2 * r + pass] = c < cap ? c : cap;
    }
    __syncthreads();
  }
}

// ------------- decode: xhat/auxo from (idx,val) lists; no VGPR cap ----
__global__ __launch_bounds__(256) void k_decode(
    const int* __restrict__ cnts, const int* __restrict__ mIdxG,
    const float* __restrict__ mValG, const int* __restrict__ aIdxG,
    const float* __restrict__ aValG, const float* __restrict__ bvec,
    const __bf16* __restrict__ Wt, const float* __restrict__ Wd,
    float* __restrict__ xhat, float* __restrict__ auxo) {
  const int r = blockIdx.x, t = threadIdx.x;
  __shared__ int sMi[MAIN_CAP];
  __shared__ float sMv[MAIN_CAP];
  __shared__ int sAi[AUX_CAP];
  __shared__ float sAv[AUX_CAP];
  int kc = cnts[2 * r], ac = cnts[2 * r + 1];
  if (t < MAIN_CAP && t < kc) { sMi[t] = mIdxG[r * MAIN_CAP + t]; sMv[t] = mValG[r * MAIN_CAP + t]; }
  for (int i = t; i < ac; i += 256) { sAi[i] = aIdxG[r * AUX_CAP + i]; sAv[i] = aValG[r * AUX_CAP + i]; }
  __syncthreads();

  float o0 = 0.f, o1 = 0.f, o2 = 0.f;   // cols t, t+256, t+512
  float a0 = 0.f, a1 = 0.f, a2 = 0.f;
  if (Wt) {
    int i = 0;
    for (; i + 4 <= kc; i += 4) {
      int i0 = sMi[i], i1 = sMi[i + 1], i2 = sMi[i + 2], i3 = sMi[i + 3];
      float v0 = sMv[i], v1 = sMv[i + 1], v2 = sMv[i + 2], v3 = sMv[i + 3];
      const __bf16* p0 = Wt + (size_t)i0 * NIN;
      const __bf16* p1 = Wt + (size_t)i1 * NIN;
      const __bf16* p2 = Wt + (size_t)i2 * NIN;
      const __bf16* p3 = Wt + (size_t)i3 * NIN;
      float w00 = p0[t], w01 = p0[t + 256], w02 = p0[t + 512];
      float w10 = p1[t], w11 = p1[t + 256], w12 = p1[t + 512];
      float w20 = p2[t], w21 = p2[t + 256], w22 = p2[t + 512];
      float w30 = p3[t], w31 = p3[t + 256], w32 = p3[t + 512];
      o0 = fmaf(v0, w00, o0); o1 = fmaf(v0, w01, o1); o2 = fmaf(v0, w02, o2);
      o0 = fmaf(v1, w10, o0); o1 = fmaf(v1, w11, o1); o2 = fmaf(v1, w12, o2);
      o0 = fmaf(v2, w20, o0); o1 = fmaf(v2, w21, o1); o2 = fmaf(v2, w22, o2);
      o0 = fmaf(v3, w30, o0); o1 = fmaf(v3, w31, o1); o2 = fmaf(v3, w32, o2);
    }
    for (; i < kc; ++i) {
      const __bf16* p = Wt + (size_t)sMi[i] * NIN;
      float v = sMv[i];
      o0 = fmaf(v, (float)p[t], o0);
      o1 = fmaf(v, (float)p[t + 256], o1);
      o2 = fmaf(v, (float)p[t + 512], o2);
    }
    i = 0;
    for (; i + 4 <= ac; i += 4) {
      int i0 = sAi[i], i1 = sAi[i + 1], i2 = sAi[i + 2], i3 = sAi[i + 3];
      float v0 = sAv[i], v1 = sAv[i + 1], v2 = sAv[i + 2], v3 = sAv[i + 3];
      const __bf16* p0 = Wt + (size_t)i0 * NIN;
      const __bf16* p1 = Wt + (size_t)i1 * NIN;
      const __bf16* p2 = Wt + (size_t)i2 * NIN;
      const __bf16* p3 = Wt + (size_t)i3 * NIN;
      float w00 = p0[t], w01 = p0[t + 256], w02 = p0[t + 512];
      float w10 = p1[t], w11 = p1[t + 256], w12 = p1[t + 512];
      float w20 = p2[t], w21 = p2[t + 256], w22 = p2[t + 512];
      float w30 = p3[t], w31 = p3[t + 256], w32 = p3[t + 512];
      a0 = fmaf(v0, w00, a0); a1 = fmaf(v0, w01, a1); a2 = fmaf(v0, w02, a2);
      a0 = fmaf(v1, w10, a0); a1 = fmaf(v1, w11, a1); a2 = fmaf(v1, w12, a2);
      a0 = fmaf(v2, w20, a0); a1 = fmaf(v2, w21, a1); a2 = fmaf(v2, w22, a2);
      a0 = fmaf(v3, w30, a0); a1 = fmaf(v3, w31, a1); a2 = fmaf(v3, w32, a2);
    }
    for (; i < ac; ++i) {
      const __bf16* p = Wt + (size_t)sAi[i] * NIN;
      float v = sAv[i];
      a0 = fmaf(v, (float)p[t], a0);
      a1 = fmaf(v, (float)p[t + 256], a1);
      a2 = fmaf(v, (float)p[t + 512], a2);
    }
  } else {  // fallback: strided gather from W_dec [NIN][NLAT]
    for (int i = 0; i < kc; ++i) {
      float v = sMv[i]; int ix = sMi[i];
      o0 = fmaf(v, Wd[(size_t)t * NLAT + ix], o0);
      o1 = fmaf(v, Wd[(size_t)(t + 256) * NLAT + ix], o1);
      o2 = fmaf(v, Wd[(size_t)(t + 512) * NLAT + ix], o2);
    }
    for (int i = 0; i < ac; ++i) {
      float v = sAv[i]; int ix = sAi[i];
      a0 = fmaf(v, Wd[(size_t)t * NLAT + ix], a0);
      a1 = fmaf(v, Wd[(size_t)(t + 256) * NLAT + ix], a1);
      a2 = fmaf(v, Wd[(size_t)(t + 512) * NLAT + ix], a2);
    }
  }
  float b0 = bvec[t], b1 = bvec[t + 256], b2 = bvec[t + 512];
  xhat[(size_t)r * NIN + t] = o0 + b0;
  xhat[(size_t)r * NIN + t + 256] = o1 + b1;
  xhat[(size_t)r * NIN + t + 512] = o2 + b2;
  auxo[(size_t)r * NIN + t] = a0 + b0;
  auxo[(size_t)r * NIN + t + 256] = a1 + b1;
  auxo[(size_t)r * NIN + t + 512] = a2 + b2;
}

extern "C" void kernel_launch(void* const* d_in, const int* in_sizes, int n_in,
                              void* d_out, int out_size, void* d_ws, size_t ws_size,
                              hipStream_t stream) {
  const float* x  = (const float*)d_in[0];
  const float* bv = (const float*)d_in[1];
  const float* We = (const float*)d_in[2];
  const float* be = (const float*)d_in[3];
  const float* Wd = (const float*)d_in[4];
  const int* miss = (const int*)d_in[5];
  const int* kp   = (const int*)d_in[6];
  const int* akp  = (const int*)d_in[7];

  float* out   = (float*)d_out;
  float* xhat  = out;                          // [4096 x 768]
  float* alpha = out + (size_t)3145728;        // [4096 x 24576]
  float* apre  = out + (size_t)103809024;      // fired_mask region; alpha_pre scratch
  float* auxo  = out + (size_t)204472320;      // [4096 x 768]

  // ws layout: dbits 64K | cnts 64K | mIdx 1M | mVal 1M | aIdx 16M | aVal 16M
  //            | Wt bf16 36M | A2 12M | B2 72M   (~154 MB total)
  char* wsb = (char*)d_ws;
  unsigned* dbits = (unsigned*)wsb;
  int*   cnts  = (int*)(wsb + 65536);
  int*   mIdxG = (int*)(wsb + 131072);
  float* mValG = (float*)(wsb + 131072 + (size_t)NB * MAIN_CAP * 4);
  int*   aIdxG = (int*)(wsb + 131072 + (size_t)NB * MAIN_CAP * 8);
  float* aValG = (float*)(wsb + 131072 + (size_t)NB * MAIN_CAP * 8 + (size_t)NB * AUX_CAP * 4);
  size_t offWt = 131072 + (size_t)NB * MAIN_CAP * 8 + (size_t)NB * AUX_CAP * 8;
  size_t offA2 = offWt + (size_t)NLAT * NIN * 2;
  size_t offB2 = offA2 + (size_t)NB * K2 * 2;
  size_t needFull = offB2 + (size_t)NLAT * K2 * 2;
  bool haveWt   = ws_size >= offA2;
  bool haveFull = ws_size >= needFull;
  __bf16* Wt = haveWt ? (__bf16*)(wsb + offWt) : nullptr;
  __bf16* A2 = (__bf16*)(wsb + offA2);
  __bf16* B2 = (__bf16*)(wsb + offB2);

  k_deadbits<<<96, 256, 0, stream>>>(miss, dbits);
  if (haveFull) {
    k_pack_a<<<dim3(32, KT2), 256, 0, stream>>>(x, bv, A2);
    k_pack_b<<<dim3(192, KT2), 256, 0, stream>>>(We, B2);
  }
  if (haveWt)
    k_transpose<<<dim3(NLAT / 32, NIN / 32), dim3(32, 8), 0, stream>>>(Wd, Wt);

  if (haveFull)
    k_gemm_bf16<<<dim3(32, 192), 256, 0, stream>>>(A2, B2, be, apre);
  else
    k_encgemm_f32<<<dim3(NB / BM, NLAT / BN), 256, 0, stream>>>(x, bv, We, be, apre);

  k_select8<<<NB, SELT, SMEM_SEL, stream>>>(apre, x, bv, We, be, dbits, kp, akp,
                                            alpha, apre, cnts, mIdxG, mValG,
                                            aIdxG, aValG);
  k_decode<<<NB, 256, 0, stream>>>(cnts, mIdxG, mValG, aIdxG, aValG, bv,
                                   Wt, Wd, xhat, auxo);
}

// Round 10
// 2329.927 us; speedup vs baseline: 3.3662x; 1.0729x over previous
//
#include <hip/hip_runtime.h>
#include <math.h>

#define NB   4096
#define NIN  768
#define NLAT 24576
#define K2   1536   // [Ah|Al] x [Bh|Bh]
#define KT2  24     // K2/64

// f32 fallback GEMM tiling
#define BM 128
#define BN 128
#define BK 16
#define LDT 132

#define CAND_CAP 512
#define BAND_CAP 160
#define MAIN_CAP 64
#define AUX_CAP  1024
#define SELT     1024
#define GRP      6      // uint4 groups per thread (24 elems)

// dynamic LDS layout for k_select9
#define OFF_KEYS 0                  // uint[24576] = 98304
#define OFF_REDI 98304              // int[48]
#define OFF_REDF 98496              // float[128]
#define OFF_CTRL 99008              // int[32] (ctrlF aliases)
#define OFF_PCNT 99136              // int[16][6]
#define OFF_CKM  99520              // unsigned[512]
#define OFF_CIM  101568             // int[512]
#define OFF_CKA  103616             // unsigned[512]
#define OFF_CIA  105664             // int[512]
#define OFF_BIM  107712             // int[160]
#define OFF_BIA  108352             // int[160]
#define OFF_BVM  108992             // double[160] (8B aligned)
#define OFF_BVA  110272             // double[160]
#define OFF_BSM  111552             // uchar[160]
#define OFF_BSA  111712             // uchar[160]
#define SMEM_SEL 111872

typedef __bf16 bf16x8 __attribute__((ext_vector_type(8)));
typedef float  f32x4  __attribute__((ext_vector_type(4)));

__device__ __forceinline__ unsigned fkey(float f) {
  unsigned u = __float_as_uint(f);
  return u ^ ((unsigned)((int)u >> 31) | 0x80000000u);  // monotone total order
}
__device__ __forceinline__ float keyinv(unsigned u) {
  unsigned s = (u & 0x80000000u) ? (u ^ 0x80000000u) : ~u;
  return __uint_as_float(s);
}
// upper-tail inverse normal (Hastings approx): count_frac_above = p -> z
__device__ __forceinline__ float zup(float p) {
  p = fminf(fmaxf(p, 1e-7f), 0.5f);
  float t = sqrtf(-2.0f * logf(p));
  return t - (2.30753f + 0.27061f * t) / (1.0f + 0.99229f * t + 0.04481f * t * t);
}

#define GLOAD16(g, l) __builtin_amdgcn_global_load_lds( \
    (const __attribute__((address_space(1))) unsigned int*)(g), \
    (__attribute__((address_space(3))) unsigned int*)(l), 16, 0, 0)

// ---------------- dead bitset: bit j = (miss[j] >= 1) ----------------
__global__ __launch_bounds__(256) void k_deadbits(const int* __restrict__ miss,
                                                  unsigned* __restrict__ bits) {
  int j = blockIdx.x * 256 + threadIdx.x;
  unsigned long long b = __ballot(miss[j] >= 1);
  if ((threadIdx.x & 63) == 0) {
    int w = j >> 5;
    bits[w] = (unsigned)b;
    bits[w + 1] = (unsigned)(b >> 32);
  }
}

// ---------------- W_dec [NIN][NLAT] -> Wt [NLAT][NIN] (bf16) ----------------
__global__ __launch_bounds__(256) void k_transpose(const float* __restrict__ src,
                                                   __bf16* __restrict__ dst) {
  __shared__ float tile[32][33];
  int bx = blockIdx.x * 32;  // NLAT
  int by = blockIdx.y * 32;  // NIN
  int tx = threadIdx.x, ty = threadIdx.y;
  for (int i = ty; i < 32; i += 8)
    tile[i][tx] = src[(size_t)(by + i) * NLAT + bx + tx];
  __syncthreads();
  for (int i = ty; i < 32; i += 8)
    dst[(size_t)(bx + i) * NIN + by + tx] = (__bf16)tile[tx][i];
}

// ---- pack (x-b) into A2 tiles [mt][kt][128][64], pre-swizzled LDS image ----
__global__ __launch_bounds__(256) void k_pack_a(const float* __restrict__ x,
    const float* __restrict__ bvec, __bf16* __restrict__ A2) {
  const int mt = blockIdx.x, kt = blockIdx.y, t = threadIdx.x;
  __bf16* out = A2 + (((size_t)mt * KT2 + kt) << 13);
#pragma unroll
  for (int i = 0; i < 32; ++i) {
    int idx = i * 256 + t;
    int r = idx >> 6, c2 = idx & 63;
    int kk = c2 ^ ((r & 7) << 3);
    int kg = kt * 64 + kk;
    int k = kg >= 768 ? kg - 768 : kg;
    bool lo = (kg >= 768);                            // A = [Ah | Al]
    float v = x[(size_t)(mt * 128 + r) * NIN + k] - bvec[k];
    __bf16 h = (__bf16)v;
    out[idx] = lo ? (__bf16)(v - (float)h) : h;
  }
}

__global__ __launch_bounds__(256) void k_pack_b(const float* __restrict__ We,
    __bf16* __restrict__ B2) {
  const int nt = blockIdx.x, kt = blockIdx.y, t = threadIdx.x;
  __bf16* out = B2 + (((size_t)nt * KT2 + kt) << 13);
#pragma unroll
  for (int i = 0; i < 32; ++i) {
    int idx = i * 256 + t;
    int r = idx >> 6, c2 = idx & 63;
    int kk = c2 ^ ((r & 7) << 3);
    int kg = kt * 64 + kk;
    int k = kg >= 768 ? kg - 768 : kg;                // B = [Bh | Bh]
    float v = We[(size_t)(nt * 128 + r) * NIN + k];
    out[idx] = (__bf16)v;
  }
}

// ---------------- bf16 MFMA GEMM: apre = A2 @ B2^T + be ----------------
__global__ __launch_bounds__(256) void k_gemm_bf16(
    const __bf16* __restrict__ A2, const __bf16* __restrict__ B2,
    const float* __restrict__ be, float* __restrict__ apre) {
  __shared__ char sA[16384];
  __shared__ char sB[16384];
  const int t = threadIdx.x;
  const int lane = t & 63, wave = t >> 6;
  const int mt = blockIdx.x, nt = blockIdx.y;
  const int wm = wave >> 1, wn = wave & 1;

  int aoff[4][2], boff[4][2];
#pragma unroll
  for (int f = 0; f < 4; ++f) {
    int ra = wm * 64 + f * 16 + (lane & 15);
    int rb = wn * 64 + f * 16 + (lane & 15);
#pragma unroll
    for (int kk = 0; kk < 2; ++kk) {
      int c = kk * 64 + (lane >> 4) * 16;
      aoff[f][kk] = ra * 128 + (c ^ ((ra & 7) << 4));
      boff[f][kk] = rb * 128 + (c ^ ((rb & 7) << 4));
    }
  }
  f32x4 acc[4][4] = {};
  const char* gA = (const char*)(A2 + (((size_t)mt * KT2) << 13));
  const char* gB = (const char*)(B2 + (((size_t)nt * KT2) << 13));
  for (int kt = 0; kt < KT2; ++kt) {
    const char* tA = gA + ((size_t)kt << 14);
    const char* tB = gB + ((size_t)kt << 14);
#pragma unroll
    for (int i = 0; i < 4; ++i) {
      int chunk = (i * 4 + wave) * 1024;
      GLOAD16(tA + chunk + lane * 16, sA + chunk);
      GLOAD16(tB + chunk + lane * 16, sB + chunk);
    }
    __syncthreads();
#pragma unroll
    for (int kk = 0; kk < 2; ++kk) {
      bf16x8 a[4], b[4];
#pragma unroll
      for (int f = 0; f < 4; ++f) {
        a[f] = *(const bf16x8*)(sA + aoff[f][kk]);
        b[f] = *(const bf16x8*)(sB + boff[f][kk]);
      }
#pragma unroll
      for (int mi = 0; mi < 4; ++mi)
#pragma unroll
        for (int ni = 0; ni < 4; ++ni)
          acc[mi][ni] = __builtin_amdgcn_mfma_f32_16x16x32_bf16(a[mi], b[ni], acc[mi][ni], 0, 0, 0);
    }
    __syncthreads();
  }
  const int m0 = mt * 128 + wm * 64, n0 = nt * 128 + wn * 64;
#pragma unroll
  for (int ni = 0; ni < 4; ++ni) {
    int n = n0 + ni * 16 + (lane & 15);
    float bb = be[n];
#pragma unroll
    for (int mi = 0; mi < 4; ++mi) {
      int mbase = m0 + mi * 16 + (lane >> 4) * 4;
#pragma unroll
      for (int q = 0; q < 4; ++q)
        apre[(size_t)(mbase + q) * NLAT + n] = acc[mi][ni][q] + bb;
    }
  }
}

// ---------------- f32 fallback GEMM ----------------
__global__ __launch_bounds__(256) void k_encgemm_f32(
    const float* __restrict__ x, const float* __restrict__ bvec,
    const float* __restrict__ We, const float* __restrict__ be,
    float* __restrict__ apre) {
  __shared__ float As[BK][LDT];
  __shared__ float Bs[BK][LDT];
  const int t = threadIdx.x;
  const int m0 = blockIdx.x * BM;
  const int n0 = blockIdx.y * BN;
  const int lane = t & 63, wave = t >> 6;
  const int cn = ((wave & 1) * 8 + (lane & 7)) * 8;
  const int cm = ((wave >> 1) * 8 + (lane >> 3)) * 8;
  float acc[8][8] = {};
  const float* xb = x + (size_t)m0 * NIN;
  const float* wb = We + (size_t)n0 * NIN;
  for (int k0 = 0; k0 < NIN; k0 += BK) {
#pragma unroll
    for (int i = 0; i < 2; ++i) {
      int e = t + i * 256;
      int row = e >> 2, q = e & 3;
      float4 bv = *(const float4*)(bvec + k0 + q * 4);
      float4 av = *(const float4*)(xb + (size_t)row * NIN + k0 + q * 4);
      av.x -= bv.x; av.y -= bv.y; av.z -= bv.z; av.w -= bv.w;
      As[q * 4 + 0][row] = av.x; As[q * 4 + 1][row] = av.y;
      As[q * 4 + 2][row] = av.z; As[q * 4 + 3][row] = av.w;
      float4 wv = *(const float4*)(wb + (size_t)row * NIN + k0 + q * 4);
      Bs[q * 4 + 0][row] = wv.x; Bs[q * 4 + 1][row] = wv.y;
      Bs[q * 4 + 2][row] = wv.z; Bs[q * 4 + 3][row] = wv.w;
    }
    __syncthreads();
#pragma unroll
    for (int kk = 0; kk < BK; ++kk) {
      float a0[8], b0[8];
      *(float4*)&a0[0] = *(const float4*)&As[kk][cm];
      *(float4*)&a0[4] = *(const float4*)&As[kk][cm + 4];
      *(float4*)&b0[0] = *(const float4*)&Bs[kk][cn];
      *(float4*)&b0[4] = *(const float4*)&Bs[kk][cn + 4];
#pragma unroll
      for (int i = 0; i < 8; ++i)
#pragma unroll
        for (int j = 0; j < 8; ++j)
          acc[i][j] = fmaf(a0[i], b0[j], acc[i][j]);
    }
    __syncthreads();
  }
  float bb[8];
  *(float4*)&bb[0] = *(const float4*)(be + n0 + cn);
  *(float4*)&bb[4] = *(const float4*)(be + n0 + cn + 4);
#pragma unroll
  for (int i = 0; i < 8; ++i) {
    float4 v0 = make_float4(acc[i][0] + bb[0], acc[i][1] + bb[1],
                            acc[i][2] + bb[2], acc[i][3] + bb[3]);
    float4 v1 = make_float4(acc[i][4] + bb[4], acc[i][5] + bb[5],
                            acc[i][6] + bb[6], acc[i][7] + bb[7]);
    float* orow = apre + (size_t)(m0 + cm + i) * NLAT + n0 + cn;
    *(float4*)orow = v0;
    *(float4*)(orow + 4) = v1;
  }
}

// ------------- per-row top-k: fused main+aux passes, ~10 barrier phases ----
__global__ __launch_bounds__(SELT) void k_select9(
    const float* apre, const float* __restrict__ x,
    const float* __restrict__ bvec, const float* __restrict__ We,
    const float* __restrict__ be, const unsigned* __restrict__ dbits,
    const int* __restrict__ kptr, const int* __restrict__ akptr,
    float* __restrict__ alpha, float* mask,
    int* __restrict__ cnts, int* __restrict__ mIdxG, float* __restrict__ mValG,
    int* __restrict__ aIdxG, float* __restrict__ aValG) {
  extern __shared__ char smem[];
  uint4*    keys4 = (uint4*)(smem + OFF_KEYS);
  int*      redI  = (int*)(smem + OFF_REDI);
  float*    redF  = (float*)(smem + OFF_REDF);
  int*      ctrl  = (int*)(smem + OFF_CTRL);
  float*    ctrlF = (float*)(smem + OFF_CTRL);
  int*      pcnt  = (int*)(smem + OFF_PCNT);
  unsigned* ckM   = (unsigned*)(smem + OFF_CKM);
  int*      ciM   = (int*)(smem + OFF_CIM);
  unsigned* ckA   = (unsigned*)(smem + OFF_CKA);
  int*      ciA   = (int*)(smem + OFF_CIA);
  int*      biM   = (int*)(smem + OFF_BIM);
  int*      biA   = (int*)(smem + OFF_BIA);
  double*   bvM   = (double*)(smem + OFF_BVM);
  double*   bvA   = (double*)(smem + OFF_BVA);
  unsigned char* bsM = (unsigned char*)(smem + OFF_BSM);
  unsigned char* bsA = (unsigned char*)(smem + OFF_BSA);

  const int t = threadIdx.x;
  const int r = blockIdx.x;
  const int lane = t & 63, wave = t >> 6;   // 16 waves

  // one-time counter resets (covered by the stats barrier)
  if (t < 96) pcnt[t] = 0;
  else if (t < 106) ctrl[t - 96] = 0;       // ctrl[0..9]

  // ---- load row -> fkey -> LDS; fused stats ----
  const uint4* rowp = (const uint4*)(apre + (size_t)r * NLAT);
  unsigned dm = 0;
  float s1 = 0.f, s2 = 0.f;
  float vmxA = -INFINITY, vmnA = INFINITY, vmxD = -INFINITY, vmnD = INFINITY;
#pragma unroll
  for (int i = 0; i < GRP; ++i) {
    int g = t + SELT * i;
    uint4 rv = rowp[g];
    unsigned nb = (dbits[g >> 3] >> ((g & 7) * 4)) & 0xFu;
    dm |= nb << (4 * i);
    float vs[4] = {__uint_as_float(rv.x), __uint_as_float(rv.y),
                   __uint_as_float(rv.z), __uint_as_float(rv.w)};
    uint4 kv;
    kv.x = fkey(vs[0]); kv.y = fkey(vs[1]); kv.z = fkey(vs[2]); kv.w = fkey(vs[3]);
    keys4[g] = kv;
#pragma unroll
    for (int q = 0; q < 4; ++q) {
      float v = vs[q];
      s1 += v; s2 += v * v;
      vmxA = fmaxf(vmxA, v); vmnA = fminf(vmnA, v);
      if ((nb >> q) & 1u) { vmxD = fmaxf(vmxD, v); vmnD = fminf(vmnD, v); }
    }
  }
  int nd = __popc(dm & 0xFFFFFFu);
#pragma unroll
  for (int o = 32; o; o >>= 1) {
    s1 += __shfl_xor(s1, o); s2 += __shfl_xor(s2, o);
    vmxA = fmaxf(vmxA, __shfl_xor(vmxA, o)); vmnA = fminf(vmnA, __shfl_xor(vmnA, o));
    vmxD = fmaxf(vmxD, __shfl_xor(vmxD, o)); vmnD = fminf(vmnD, __shfl_xor(vmnD, o));
    nd += __shfl_xor(nd, o);
  }
  if (lane == 0) {
    float* rf = redF + wave * 8;
    rf[0] = s1; rf[1] = s2; rf[2] = vmxA; rf[3] = vmnA; rf[4] = vmxD; rf[5] = vmnD;
    redI[wave] = nd;
  }
  __syncthreads();
  if (wave == 0) {
    float a0 = 0.f, a1 = 0.f, a2 = -INFINITY, a3 = INFINITY, a4 = -INFINITY, a5 = INFINITY;
    int a6 = 0;
    if (lane < 16) {
      const float* rf = redF + lane * 8;
      a0 = rf[0]; a1 = rf[1]; a2 = rf[2]; a3 = rf[3]; a4 = rf[4]; a5 = rf[5];
      a6 = redI[lane];
    }
#pragma unroll
    for (int o = 32; o; o >>= 1) {
      a0 += __shfl_xor(a0, o); a1 += __shfl_xor(a1, o);
      a2 = fmaxf(a2, __shfl_xor(a2, o)); a3 = fminf(a3, __shfl_xor(a3, o));
      a4 = fmaxf(a4, __shfl_xor(a4, o)); a5 = fminf(a5, __shfl_xor(a5, o));
      a6 += __shfl_xor(a6, o);
    }
    if (lane == 0) {
      float mu = a0 / (float)NLAT;
      float var = fmaxf(a1 / (float)NLAT - mu * mu, 1e-20f);
      ctrlF[16] = mu; ctrlF[17] = sqrtf(var);
      ctrlF[18] = a3; ctrlF[19] = a2;   // vmnA, vmxA
      ctrlF[20] = a5; ctrlF[21] = a4;   // vmnD, vmxD
      ctrl[22] = a6;                    // ndead
    }
  }
  __syncthreads();

  int kmain = kptr[0]; if (kmain > MAIN_CAP) kmain = MAIN_CAP;
  int kaux  = akptr[0]; if (kaux > AUX_CAP)  kaux  = AUX_CAP;
  const float mu = ctrlF[16], sg = ctrlF[17];
  const int ndead = ctrl[22];
  int kauxE = kaux > ndead ? ndead : kaux;
  const bool mainOn = (kmain > 0);
  const bool auxOn  = (kauxE > 0);

  unsigned TloM = fkey(ctrlF[18]), ThiM = fkey(ctrlF[19]) + 1u;
  int cLoM = NLAT, cHiM = 0;
  unsigned TloA = 0u, ThiA = 2u;
  int cLoA = 0, cHiA = 0;
  if (auxOn) { TloA = fkey(ctrlF[20]); ThiA = fkey(ctrlF[21]) + 1u; cLoA = ndead; }

  // ---- fused probe: 1 barrier / iter; analytic seed on iter 0 ----
  for (int it = 0; it < 16; ++it) {
    bool actM = mainOn && (cLoM - cHiM) > (CAND_CAP - 8);
    bool actA = auxOn  && (cLoA - cHiA) > (CAND_CAP - 8);
    if (!actM && !actA) break;
    unsigned TM1 = TloM + 1u, TM2 = TM1, TM3 = TM1;
    unsigned TA1 = TloA + 1u, TA2 = TA1, TA3 = TA1;
    if (actM) {
      if (it == 0) {
        float fn = (float)NLAT;
        float v1 = mu + sg * zup(4.f * kmain / fn);
        float v2 = mu + sg * zup((float)kmain / fn);
        float v3 = mu + sg * zup(0.25f * kmain / fn);
        TM1 = fkey(v1); TM2 = fkey(v2); TM3 = fkey(v3);
        unsigned lo1 = TloM + 1u, hi1 = ThiM - 1u;
        TM1 = TM1 < lo1 ? lo1 : (TM1 > hi1 ? hi1 : TM1);
        TM2 = TM2 < TM1 ? TM1 : (TM2 > hi1 ? hi1 : TM2);
        TM3 = TM3 < TM2 ? TM2 : (TM3 > hi1 ? hi1 : TM3);
      } else {
        float vlo = keyinv(TloM), vhi = keyinv(ThiM);
        TM1 = fkey(0.75f * vlo + 0.25f * vhi);
        TM2 = fkey(0.50f * vlo + 0.50f * vhi);
        TM3 = fkey(0.25f * vlo + 0.75f * vhi);
        if (!(TM1 > TloM && TM3 < ThiM && TM1 <= TM2 && TM2 <= TM3)) actM = false;
      }
    }
    if (actA) {
      if (it == 0) {
        float fn = (float)ndead;
        float v1 = mu + sg * zup(4.f * kauxE / fn);
        float v2 = mu + sg * zup((float)kauxE / fn);
        float v3 = mu + sg * zup(0.25f * kauxE / fn);
        TA1 = fkey(v1); TA2 = fkey(v2); TA3 = fkey(v3);
        unsigned lo1 = TloA + 1u, hi1 = ThiA - 1u;
        TA1 = TA1 < lo1 ? lo1 : (TA1 > hi1 ? hi1 : TA1);
        TA2 = TA2 < TA1 ? TA1 : (TA2 > hi1 ? hi1 : TA2);
        TA3 = TA3 < TA2 ? TA2 : (TA3 > hi1 ? hi1 : TA3);
      } else {
        float vlo = keyinv(TloA), vhi = keyinv(ThiA);
        TA1 = fkey(0.75f * vlo + 0.25f * vhi);
        TA2 = fkey(0.50f * vlo + 0.50f * vhi);
        TA3 = fkey(0.25f * vlo + 0.75f * vhi);
        if (!(TA1 > TloA && TA3 < ThiA && TA1 <= TA2 && TA2 <= TA3)) actA = false;
      }
    }
    if (!actM && !actA) break;
    int cm1 = 0, cm2 = 0, cm3 = 0, ca1 = 0, ca2 = 0, ca3 = 0;
#pragma unroll
    for (int i = 0; i < GRP; ++i) {
      uint4 kv = keys4[t + SELT * i];
      unsigned nb = (dm >> (4 * i)) & 0xFu;
      unsigned ks[4] = {kv.x, kv.y, kv.z, kv.w};
#pragma unroll
      for (int q = 0; q < 4; ++q) {
        unsigned kk = ks[q];
        cm1 += (kk >= TM1); cm2 += (kk >= TM2); cm3 += (kk >= TM3);
        if ((nb >> q) & 1u) { ca1 += (kk >= TA1); ca2 += (kk >= TA2); ca3 += (kk >= TA3); }
      }
    }
#pragma unroll
    for (int o = 32; o; o >>= 1) {
      cm1 += __shfl_xor(cm1, o); cm2 += __shfl_xor(cm2, o); cm3 += __shfl_xor(cm3, o);
      ca1 += __shfl_xor(ca1, o); ca2 += __shfl_xor(ca2, o); ca3 += __shfl_xor(ca3, o);
    }
    if (lane == 0) {
      int* pc = pcnt + it * 6;
      atomicAdd(&pc[0], cm1); atomicAdd(&pc[1], cm2); atomicAdd(&pc[2], cm3);
      atomicAdd(&pc[3], ca1); atomicAdd(&pc[4], ca2); atomicAdd(&pc[5], ca3);
    }
    __syncthreads();
    const int* pc = pcnt + it * 6;
    int CM1 = pc[0], CM2 = pc[1], CM3 = pc[2];
    int CA1 = pc[3], CA2 = pc[4], CA3 = pc[5];
    if (actM) {
      if (CM3 >= kmain)      { TloM = TM3; cLoM = CM3; }
      else if (CM2 >= kmain) { TloM = TM2; cLoM = CM2; ThiM = TM3; cHiM = CM3; }
      else if (CM1 >= kmain) { TloM = TM1; cLoM = CM1; ThiM = TM2; cHiM = CM2; }
      else                   { ThiM = TM1; cHiM = CM1; }
    }
    if (actA) {
      if (CA3 >= kauxE)      { TloA = TA3; cLoA = CA3; }
      else if (CA2 >= kauxE) { TloA = TA2; cLoA = CA2; ThiA = TA3; cHiA = CA3; }
      else if (CA1 >= kauxE) { TloA = TA1; cLoA = CA1; ThiA = TA2; cHiA = CA2; }
      else                   { ThiA = TA1; cHiA = CA1; }
    }
  }

  // ---- fused extract ----
#pragma unroll
  for (int i = 0; i < GRP; ++i) {
    int g = t + SELT * i;
    uint4 kv = keys4[g];
    unsigned nb = (dm >> (4 * i)) & 0xFu;
    unsigned ks[4] = {kv.x, kv.y, kv.z, kv.w};
#pragma unroll
    for (int q = 0; q < 4; ++q) {
      unsigned kk = ks[q];
      if (mainOn && kk >= TloM && kk < ThiM) {
        int p = atomicAdd(&ctrl[0], 1);
        if (p < CAND_CAP) { ckM[p] = kk; ciM[p] = 4 * g + q; }
      }
      if (auxOn && ((nb >> q) & 1u) && kk >= TloA && kk < ThiA) {
        int p = atomicAdd(&ctrl[1], 1);
        if (p < CAND_CAP) { ckA[p] = kk; ciA[p] = 4 * g + q; }
      }
    }
  }
  __syncthreads();
  int ccM = ctrl[0] < CAND_CAP ? ctrl[0] : CAND_CAP;
  int ccA = ctrl[1] < CAND_CAP ? ctrl[1] : CAND_CAP;
  int needM = kmain - cHiM; if (needM < 1) needM = 1; if (needM > ccM) needM = ccM;
  int needA = kauxE - cHiA; if (needA < 1) needA = 1; if (needA > ccA) needA = ccA;

  // ---- parallel exact-rank (main: threads 0..; aux: threads 512..) ----
  if (t < ccM) {
    unsigned ki = ckM[t]; int ii = ciM[t];
    int rank = 0;
    for (int qq = 0; qq < ccM; ++qq) {
      unsigned kq = ckM[qq];
      rank += (kq > ki || (kq == ki && ciM[qq] < ii)) ? 1 : 0;
    }
    if (rank == needM - 1) ctrl[2] = (int)ki;
  } else if (t >= 512 && t - 512 < ccA) {
    int tt = t - 512;
    unsigned ki = ckA[tt]; int ii = ciA[tt];
    int rank = 0;
    for (int qq = 0; qq < ccA; ++qq) {
      unsigned kq = ckA[qq];
      rank += (kq > ki || (kq == ki && ciA[qq] < ii)) ? 1 : 0;
    }
    if (rank == needA - 1) ctrl[3] = (int)ki;
  }
  __syncthreads();

  // ---- fused band collect ----
  float VsM = keyinv((unsigned)ctrl[2]);
  float epsM = 1e-2f + 2e-3f * fabsf(VsM);
  unsigned KhiBM = mainOn ? fkey(VsM + epsM) : 0xFFFFFFFFu;
  unsigned KloBM = mainOn ? fkey(VsM - epsM) : 0xFFFFFFFFu;
  float VsA = keyinv((unsigned)ctrl[3]);
  float epsA = 1e-2f + 2e-3f * fabsf(VsA);
  unsigned KhiBA = auxOn ? fkey(VsA + epsA) : 0xFFFFFFFFu;
  unsigned KloBA = auxOn ? fkey(VsA - epsA) : 0xFFFFFFFFu;
  int abvM = 0, abvA = 0;
#pragma unroll
  for (int i = 0; i < GRP; ++i) {
    int g = t + SELT * i;
    uint4 kv = keys4[g];
    unsigned nb = (dm >> (4 * i)) & 0xFu;
    unsigned ks[4] = {kv.x, kv.y, kv.z, kv.w};
#pragma unroll
    for (int q = 0; q < 4; ++q) {
      unsigned kk = ks[q];
      if (mainOn) {
        if (kk > KhiBM) ++abvM;
        else if (kk >= KloBM) {
          int p = atomicAdd(&ctrl[5], 1);
          if (p < BAND_CAP) biM[p] = 4 * g + q;
        }
      }
      if (auxOn && ((nb >> q) & 1u)) {
        if (kk > KhiBA) ++abvA;
        else if (kk >= KloBA) {
          int p = atomicAdd(&ctrl[7], 1);
          if (p < BAND_CAP) biA[p] = 4 * g + q;
        }
      }
    }
  }
#pragma unroll
  for (int o = 32; o; o >>= 1) { abvM += __shfl_xor(abvM, o); abvA += __shfl_xor(abvA, o); }
  if (lane == 0) { atomicAdd(&ctrl[4], abvM); atomicAdd(&ctrl[6], abvA); }
  __syncthreads();
  int nAbM = ctrl[4], bcM = ctrl[5] < BAND_CAP ? ctrl[5] : BAND_CAP;
  int nAbA = ctrl[6], bcA = auxOn ? (ctrl[7] < BAND_CAP ? ctrl[7] : BAND_CAP) : 0;
  if (!mainOn) bcM = 0;
  int needBM = kmain - nAbM; if (needBM < 0) needBM = 0; if (needBM > bcM) needBM = bcM;
  int needBA = kauxE - nAbA; if (needBA < 0) needBA = 0; if (needBA > bcA) needBA = bcA;

  // ---- batched f64 band dots (both bands across 16 waves) ----
  {
    const float* xr = x + (size_t)r * NIN;
    float xb[NIN / 64];
#pragma unroll
    for (int jj = 0; jj < NIN / 64; ++jj) {
      int col = lane + 64 * jj;
      xb[jj] = xr[col] - bvec[col];
    }
    int tot = bcM + bcA;
    for (int m = wave; m < tot; m += 16) {
      int j = (m < bcM) ? biM[m] : biA[m - bcM];
      const float* wr = We + (size_t)j * NIN;
      double s = 0.0;
#pragma unroll
      for (int jj = 0; jj < NIN / 64; ++jj)
        s += (double)xb[jj] * (double)wr[lane + 64 * jj];
#pragma unroll
      for (int o = 32; o; o >>= 1) s += __shfl_xor(s, o);
      if (lane == 0) {
        if (m < bcM) bvM[m] = s + (double)be[j];
        else bvA[m - bcM] = s + (double)be[j];
      }
    }
  }
  __syncthreads();
  // ---- parallel band ranks ----
  if (t < bcM) {
    double vi = bvM[t]; int ii = biM[t];
    double tie = fabs(vi) * 4e-8 + 1e-12;
    int rank = 0;
    for (int qq = 0; qq < bcM; ++qq) {
      double d = bvM[qq] - vi;
      rank += ((fabs(d) <= tie) ? (biM[qq] < ii) : (d > 0.0)) ? 1 : 0;
    }
    bsM[t] = (rank < needBM) ? 1 : 0;
  } else if (t >= 512 && t - 512 < bcA) {
    int tt = t - 512;
    double vi = bvA[tt]; int ii = biA[tt];
    double tie = fabs(vi) * 4e-8 + 1e-12;
    int rank = 0;
    for (int qq = 0; qq < bcA; ++qq) {
      double d = bvA[qq] - vi;
      rank += ((fabs(d) <= tie) ? (biA[qq] < ii) : (d > 0.0)) ? 1 : 0;
    }
    bsA[tt] = (rank < needBA) ? 1 : 0;
  }
  __syncthreads();

  // ---- fused emit ----
  {
    float4* arow = (float4*)(alpha + (size_t)r * NLAT);
    float4* mrow = (float4*)(mask + (size_t)r * NLAT);
#pragma unroll
    for (int i = 0; i < GRP; ++i) {
      int g = t + SELT * i;
      uint4 kv = keys4[g];
      unsigned nb = (dm >> (4 * i)) & 0xFu;
      unsigned ks[4] = {kv.x, kv.y, kv.z, kv.w};
      float av[4], mv[4];
#pragma unroll
      for (int q = 0; q < 4; ++q) {
        unsigned kk = ks[q];
        int j = 4 * g + q;
        float v = keyinv(kk);
        // main
        bool selM = mainOn && (kk > KhiBM);
        if (mainOn && !selM && kk >= KloBM) {
          for (int m2 = 0; m2 < bcM; ++m2)
            if (biM[m2] == j) { selM = bsM[m2] != 0; break; }
        }
        bool nz = selM && (v != 0.0f);
        av[q] = selM ? v : 0.0f;
        mv[q] = nz ? 1.0f : 0.0f;
        if (nz) {
          int p = atomicAdd(&ctrl[8], 1);
          if (p < MAIN_CAP) { mIdxG[r * MAIN_CAP + p] = j; mValG[r * MAIN_CAP + p] = v; }
        }
        // aux
        if (auxOn && ((nb >> q) & 1u)) {
          bool selA = kk > KhiBA;
          if (!selA && kk >= KloBA) {
            for (int m2 = 0; m2 < bcA; ++m2)
              if (biA[m2] == j) { selA = bsA[m2] != 0; break; }
          }
          if (selA && v != 0.0f) {
            int p = atomicAdd(&ctrl[9], 1);
            if (p < AUX_CAP) { aIdxG[r * AUX_CAP + p] = j; aValG[r * AUX_CAP + p] = v; }
          }
        }
      }
      arow[g] = make_float4(av[0], av[1], av[2], av[3]);
      mrow[g] = make_float4(mv[0], mv[1], mv[2], mv[3]);
    }
  }
  __syncthreads();
  if (t == 0) {
    cnts[2 * r] = ctrl[8] < MAIN_CAP ? ctrl[8] : MAIN_CAP;
    cnts[2 * r + 1] = auxOn ? (ctrl[9] < AUX_CAP ? ctrl[9] : AUX_CAP) : 0;
  }
}

// ------------- decode: xhat/auxo from (idx,val) lists; no VGPR cap ----
__global__ __launch_bounds__(256) void k_decode(
    const int* __restrict__ cnts, const int* __restrict__ mIdxG,
    const float* __restrict__ mValG, const int* __restrict__ aIdxG,
    const float* __restrict__ aValG, const float* __restrict__ bvec,
    const __bf16* __restrict__ Wt, const float* __restrict__ Wd,
    float* __restrict__ xhat, float* __restrict__ auxo) {
  const int r = blockIdx.x, t = threadIdx.x;
  __shared__ int sMi[MAIN_CAP];
  __shared__ float sMv[MAIN_CAP];
  __shared__ int sAi[AUX_CAP];
  __shared__ float sAv[AUX_CAP];
  int kc = cnts[2 * r], ac = cnts[2 * r + 1];
  if (t < MAIN_CAP && t < kc) { sMi[t] = mIdxG[r * MAIN_CAP + t]; sMv[t] = mValG[r * MAIN_CAP + t]; }
  for (int i = t; i < ac; i += 256) { sAi[i] = aIdxG[r * AUX_CAP + i]; sAv[i] = aValG[r * AUX_CAP + i]; }
  __syncthreads();

  float o0 = 0.f, o1 = 0.f, o2 = 0.f;   // cols t, t+256, t+512
  float a0 = 0.f, a1 = 0.f, a2 = 0.f;
  if (Wt) {
    int i = 0;
    for (; i + 4 <= kc; i += 4) {
      int i0 = sMi[i], i1 = sMi[i + 1], i2 = sMi[i + 2], i3 = sMi[i + 3];
      float v0 = sMv[i], v1 = sMv[i + 1], v2 = sMv[i + 2], v3 = sMv[i + 3];
      const __bf16* p0 = Wt + (size_t)i0 * NIN;
      const __bf16* p1 = Wt + (size_t)i1 * NIN;
      const __bf16* p2 = Wt + (size_t)i2 * NIN;
      const __bf16* p3 = Wt + (size_t)i3 * NIN;
      float w00 = p0[t], w01 = p0[t + 256], w02 = p0[t + 512];
      float w10 = p1[t], w11 = p1[t + 256], w12 = p1[t + 512];
      float w20 = p2[t], w21 = p2[t + 256], w22 = p2[t + 512];
      float w30 = p3[t], w31 = p3[t + 256], w32 = p3[t + 512];
      o0 = fmaf(v0, w00, o0); o1 = fmaf(v0, w01, o1); o2 = fmaf(v0, w02, o2);
      o0 = fmaf(v1, w10, o0); o1 = fmaf(v1, w11, o1); o2 = fmaf(v1, w12, o2);
      o0 = fmaf(v2, w20, o0); o1 = fmaf(v2, w21, o1); o2 = fmaf(v2, w22, o2);
      o0 = fmaf(v3, w30, o0); o1 = fmaf(v3, w31, o1); o2 = fmaf(v3, w32, o2);
    }
    for (; i < kc; ++i) {
      const __bf16* p = Wt + (size_t)sMi[i] * NIN;
      float v = sMv[i];
      o0 = fmaf(v, (float)p[t], o0);
      o1 = fmaf(v, (float)p[t + 256], o1);
      o2 = fmaf(v, (float)p[t + 512], o2);
    }
    i = 0;
    for (; i + 4 <= ac; i += 4) {
      int i0 = sAi[i], i1 = sAi[i + 1], i2 = sAi[i + 2], i3 = sAi[i + 3];
      float v0 = sAv[i], v1 = sAv[i + 1], v2 = sAv[i + 2], v3 = sAv[i + 3];
      const __bf16* p0 = Wt + (size_t)i0 * NIN;
      const __bf16* p1 = Wt + (size_t)i1 * NIN;
      const __bf16* p2 = Wt + (size_t)i2 * NIN;
      const __bf16* p3 = Wt + (size_t)i3 * NIN;
      float w00 = p0[t], w01 = p0[t + 256], w02 = p0[t + 512];
      float w10 = p1[t], w11 = p1[t + 256], w12 = p1[t + 512];
      float w20 = p2[t], w21 = p2[t + 256], w22 = p2[t + 512];
      float w30 = p3[t], w31 = p3[t + 256], w32 = p3[t + 512];
      a0 = fmaf(v0, w00, a0); a1 = fmaf(v0, w01, a1); a2 = fmaf(v0, w02, a2);
      a0 = fmaf(v1, w10, a0); a1 = fmaf(v1, w11, a1); a2 = fmaf(v1, w12, a2);
      a0 = fmaf(v2, w20, a0); a1 = fmaf(v2, w21, a1); a2 = fmaf(v2, w22, a2);
      a0 = fmaf(v3, w30, a0); a1 = fmaf(v3, w31, a1); a2 = fmaf(v3, w32, a2);
    }
    for (; i < ac; ++i) {
      const __bf16* p = Wt + (size_t)sAi[i] * NIN;
      float v = sAv[i];
      a0 = fmaf(v, (float)p[t], a0);
      a1 = fmaf(v, (float)p[t + 256], a1);
      a2 = fmaf(v, (float)p[t + 512], a2);
    }
  } else {  // fallback: strided gather from W_dec [NIN][NLAT]
    for (int i = 0; i < kc; ++i) {
      float v = sMv[i]; int ix = sMi[i];
      o0 = fmaf(v, Wd[(size_t)t * NLAT + ix], o0);
      o1 = fmaf(v, Wd[(size_t)(t + 256) * NLAT + ix], o1);
      o2 = fmaf(v, Wd[(size_t)(t + 512) * NLAT + ix], o2);
    }
    for (int i = 0; i < ac; ++i) {
      float v = sAv[i]; int ix = sAi[i];
      a0 = fmaf(v, Wd[(size_t)t * NLAT + ix], a0);
      a1 = fmaf(v, Wd[(size_t)(t + 256) * NLAT + ix], a1);
      a2 = fmaf(v, Wd[(size_t)(t + 512) * NLAT + ix], a2);
    }
  }
  float b0 = bvec[t], b1 = bvec[t + 256], b2 = bvec[t + 512];
  xhat[(size_t)r * NIN + t] = o0 + b0;
  xhat[(size_t)r * NIN + t + 256] = o1 + b1;
  xhat[(size_t)r * NIN + t + 512] = o2 + b2;
  auxo[(size_t)r * NIN + t] = a0 + b0;
  auxo[(size_t)r * NIN + t + 256] = a1 + b1;
  auxo[(size_t)r * NIN + t + 512] = a2 + b2;
}

extern "C" void kernel_launch(void* const* d_in, const int* in_sizes, int n_in,
                              void* d_out, int out_size, void* d_ws, size_t ws_size,
                              hipStream_t stream) {
  const float* x  = (const float*)d_in[0];
  const float* bv = (const float*)d_in[1];
  const float* We = (const float*)d_in[2];
  const float* be = (const float*)d_in[3];
  const float* Wd = (const float*)d_in[4];
  const int* miss = (const int*)d_in[5];
  const int* kp   = (const int*)d_in[6];
  const int* akp  = (const int*)d_in[7];

  float* out   = (float*)d_out;
  float* xhat  = out;                          // [4096 x 768]
  float* alpha = out + (size_t)3145728;        // [4096 x 24576]
  float* apre  = out + (size_t)103809024;      // fired_mask region; alpha_pre scratch
  float* auxo  = out + (size_t)204472320;      // [4096 x 768]

  // ws layout: dbits 64K | cnts 64K | mIdx 1M | mVal 1M | aIdx 16M | aVal 16M
  //            | Wt bf16 36M | A2 12M | B2 72M   (~154 MB total)
  char* wsb = (char*)d_ws;
  unsigned* dbits = (unsigned*)wsb;
  int*   cnts  = (int*)(wsb + 65536);
  int*   mIdxG = (int*)(wsb + 131072);
  float* mValG = (float*)(wsb + 131072 + (size_t)NB * MAIN_CAP * 4);
  int*   aIdxG = (int*)(wsb + 131072 + (size_t)NB * MAIN_CAP * 8);
  float* aValG = (float*)(wsb + 131072 + (size_t)NB * MAIN_CAP * 8 + (size_t)NB * AUX_CAP * 4);
  size_t offWt = 131072 + (size_t)NB * MAIN_CAP * 8 + (size_t)NB * AUX_CAP * 8;
  size_t offA2 = offWt + (size_t)NLAT * NIN * 2;
  size_t offB2 = offA2 + (size_t)NB * K2 * 2;
  size_t needFull = offB2 + (size_t)NLAT * K2 * 2;
  bool haveWt   = ws_size >= offA2;
  bool haveFull = ws_size >= needFull;
  __bf16* Wt = haveWt ? (__bf16*)(wsb + offWt) : nullptr;
  __bf16* A2 = (__bf16*)(wsb + offA2);
  __bf16* B2 = (__bf16*)(wsb + offB2);

  k_deadbits<<<96, 256, 0, stream>>>(miss, dbits);
  if (haveFull) {
    k_pack_a<<<dim3(32, KT2), 256, 0, stream>>>(x, bv, A2);
    k_pack_b<<<dim3(192, KT2), 256, 0, stream>>>(We, B2);
  }
  if (haveWt)
    k_transpose<<<dim3(NLAT / 32, NIN / 32), dim3(32, 8), 0, stream>>>(Wd, Wt);

  if (haveFull)
    k_gemm_bf16<<<dim3(32, 192), 256, 0, stream>>>(A2, B2, be, apre);
  else
    k_encgemm_f32<<<dim3(NB / BM, NLAT / BN), 256, 0, stream>>>(x, bv, We, be, apre);

  k_select9<<<NB, SELT, SMEM_SEL, stream>>>(apre, x, bv, We, be, dbits, kp, akp,
                                            alpha, apre, cnts, mIdxG, mValG,
                                            aIdxG, aValG);
  k_decode<<<NB, 256, 0, stream>>>(cnts, mIdxG, mValG, aIdxG, aValG, bv,
                                   Wt, Wd, xhat, auxo);
}